// Round 1
// baseline (5419.294 us; speedup 1.0000x reference)
//
#include <hip/hip_runtime.h>

#define Sq 2048
#define Dq 64
#define NH 64                    // B*H heads
#define QBLK 64                  // Q rows per block (4 waves x 16)
#define KVBLK 64                 // KV rows per iteration
#define NKVIT (Sq / KVBLK)       // 32
#define NQB (Sq / QBLK)          // 32 q-blocks per head
#define NBLK (NH * NQB)          // 2048 blocks
#define NROWS (NH * Sq)          // 131072 query rows
#define PT_STRIDE 72             // P lds row stride (bf16 elems): 144B, 16B-aligned, conflict-free reads

typedef __attribute__((ext_vector_type(8))) short bf16x8;   // 8 bf16 = 4 VGPR
typedef __attribute__((ext_vector_type(4))) float f32x4;    // MFMA acc

// ---------- bf16 helpers ----------
__device__ __forceinline__ float bflo(unsigned int u) {
    union { unsigned int i; float f; } x; x.i = u << 16; return x.f;
}
__device__ __forceinline__ float bfhi(unsigned int u) {
    union { unsigned int i; float f; } x; x.i = u & 0xffff0000u; return x.f;
}
__device__ __forceinline__ unsigned int f2bf(float f) {
    union { float f; unsigned int i; } x; x.f = f;
    return (x.i + 0x7fffu + ((x.i >> 16) & 1u)) >> 16;   // RNE
}

// ---------- dtype detector (unchanged; deterministic) ----------
__global__ void detect_dtype(const unsigned int* __restrict__ Q,
                             int* __restrict__ flag) {
    unsigned int u = Q[threadIdx.x];
    float a = fabsf(bflo(u));
    bool sane = (a >= 9.3e-10f) && (a <= 64.0f);
    unsigned long long b = __ballot(sane);
    if (threadIdx.x == 0) *flag = (__builtin_popcountll(b) >= 48) ? 1 : 0;
}

// ---------- async global->LDS, 16B per lane ----------
__device__ __forceinline__ void gload_lds16(const unsigned short* g, unsigned short* l) {
    __builtin_amdgcn_global_load_lds(
        (const __attribute__((address_space(1))) void*)g,
        (__attribute__((address_space(3))) void*)l, 16, 0, 0);
}

// Vt (= V^T [d][kv]) element index with XOR swizzle.
// Swizzle ((d&7)^((d>>3)&7))<<3 elems (<<4 bytes): column-writes (8 lanes, d=8*(lane&7)+e)
// spread via (d>>3); row-reads (16 lanes, d=dt*16+l15) spread via (d&7). Both <=2-way.
__device__ __forceinline__ int vt_swz(int d, int kv) {
    return (d * KVBLK + kv) ^ ((((d & 7) ^ ((d >> 3) & 7))) << 3);
}

// ---------- MFMA flash-attention (bf16 inputs) ----------
__global__ __launch_bounds__(256, 3) void fa_mfma(
    const unsigned short* __restrict__ Q, const unsigned short* __restrict__ K,
    const unsigned short* __restrict__ V, unsigned short* __restrict__ O,
    const int* __restrict__ flag)
{
    if (!(*flag)) return;   // fp32 data -> fallback kernel handles it

    __shared__ __align__(16) unsigned short Kt[KVBLK * Dq];        // 8 KiB, xor-swizzled rows
    __shared__ __align__(16) unsigned short Vt[Dq * KVBLK];        // 8 KiB, V^T, xor-swizzled
    __shared__ __align__(16) unsigned short Pl[4][16 * PT_STRIDE]; // 9 KiB, per-wave P

    const int tid  = threadIdx.x;
    const int lane = tid & 63;
    const int w    = tid >> 6;       // wave 0..3
    const int l15  = lane & 15;
    const int lg   = lane >> 4;      // 0..3

    // XCD-aware bijective swizzle: 2048 blocks = 8 XCDs x 256.
    // Each XCD gets 8 consecutive heads -> its KV working set (4 MiB) fits its L2.
    const int bid  = (int)blockIdx.x;
    const int blk  = (bid & 7) * (NBLK / 8) + (bid >> 3);
    const int head = blk >> 5;               // 32 q-blocks per head
    const int q0   = (blk & 31) * QBLK;
    const size_t hb = (size_t)head * (Sq * Dq);

    // ---- Q fragments, held in registers for the whole kernel ----
    // A-frag layout (16x16x32): lane holds A row (lane&15), k = (lane>>4)*8 + j, slice s adds s*32.
    bf16x8 qf[2];
    {
        const bf16x8* qp = (const bf16x8*)(Q + hb + (size_t)(q0 + w * 16 + l15) * Dq);
        qf[0] = qp[lg];       // k = 0..31
        qf[1] = qp[4 + lg];   // k = 32..63
    }

    // O accumulators: 4 d-tiles of 16x16; C/D layout col=lane&15 (d), row=lg*4+reg (q-row)
    f32x4 oacc[4];
    #pragma unroll
    for (int dt = 0; dt < 4; ++dt) oacc[dt] = (f32x4){0.f, 0.f, 0.f, 0.f};
    float mrow[4], lrow[4];
    #pragma unroll
    for (int r = 0; r < 4; ++r) { mrow[r] = -1e30f; lrow[r] = 0.f; }

    // staging roles: thread -> (row-in-chunk, 16B chunk-in-row)
    const int sr = tid >> 3;   // 0..31
    const int sc = tid & 7;    // 0..7
    // K source column pre-swizzle (inverse of read swizzle; rule #21: linear LDS dest)
    const int kswz_elem = (sc * 8) ^ ((sr & 7) << 3);

    for (int it = 0; it < NKVIT; ++it) {
        const int kv0 = it * KVBLK;

        __syncthreads();   // previous iteration's LDS reads done before overwrite

        // ---- stage K tile via global_load_lds (2 x 16B per thread) ----
        #pragma unroll
        for (int c = 0; c < 2; ++c) {
            gload_lds16(K + hb + (size_t)(kv0 + c * 32 + sr) * Dq + kswz_elem,
                        Kt + c * 2048 + tid * 8);
        }
        // ---- stage V tile to registers (coalesced row-major) ----
        uint4 vreg[2];
        #pragma unroll
        for (int c = 0; c < 2; ++c)
            vreg[c] = *(const uint4*)(V + hb + (size_t)(kv0 + c * 32 + sr) * Dq + sc * 8);

        asm volatile("s_waitcnt vmcnt(0)" ::: "memory");   // K in LDS, V in regs

        // ---- transpose-write V into Vt[d][kv] (swizzled, ~2-way max) ----
        #pragma unroll
        for (int c = 0; c < 2; ++c) {
            const int kv = c * 32 + sr;
            unsigned int vu[4] = { vreg[c].x, vreg[c].y, vreg[c].z, vreg[c].w };
            #pragma unroll
            for (int e2 = 0; e2 < 4; ++e2) {
                const int d0 = sc * 8 + e2 * 2;
                Vt[vt_swz(d0,     kv)] = (unsigned short)(vu[e2] & 0xffffu);
                Vt[vt_swz(d0 + 1, kv)] = (unsigned short)(vu[e2] >> 16);
            }
        }

        __syncthreads();   // Kt + Vt visible to all waves

        // ---- QK^T: S[16 q][64 kv] per wave ----
        f32x4 sacc[4];
        #pragma unroll
        for (int nt = 0; nt < 4; ++nt) sacc[nt] = (f32x4){0.f, 0.f, 0.f, 0.f};
        #pragma unroll
        for (int s = 0; s < 2; ++s) {
            #pragma unroll
            for (int nt = 0; nt < 4; ++nt) {
                const int n = nt * 16 + l15;   // kv row within tile = B col
                bf16x8 kf = *(const bf16x8*)(Kt + n * 64 + ((s * 32 + lg * 8) ^ ((n & 7) << 3)));
                sacc[nt] = __builtin_amdgcn_mfma_f32_16x16x32_bf16(qf[s], kf, sacc[nt], 0, 0, 0);
            }
        }
        #pragma unroll
        for (int nt = 0; nt < 4; ++nt) sacc[nt] *= 0.125f;   // 1/sqrt(64)

        // ---- online softmax (row r lives in 16-lane group, reg r&3) ----
        float mnew[4], alpha[4];
        #pragma unroll
        for (int r = 0; r < 4; ++r) {
            float t = fmaxf(fmaxf(sacc[0][r], sacc[1][r]), fmaxf(sacc[2][r], sacc[3][r]));
            #pragma unroll
            for (int msk = 1; msk <= 8; msk <<= 1)
                t = fmaxf(t, __shfl_xor(t, msk, 64));
            mnew[r]  = fmaxf(mrow[r], t);
            alpha[r] = __expf(mrow[r] - mnew[r]);
            mrow[r]  = mnew[r];
        }
        float psum[4] = {0.f, 0.f, 0.f, 0.f};
        #pragma unroll
        for (int nt = 0; nt < 4; ++nt) {
            #pragma unroll
            for (int r = 0; r < 4; ++r) {
                float p = __expf(sacc[nt][r] - mnew[r]);
                sacc[nt][r] = p;
                psum[r] += p;
            }
        }
        #pragma unroll
        for (int r = 0; r < 4; ++r) {
            float t = psum[r];
            #pragma unroll
            for (int msk = 1; msk <= 8; msk <<= 1)
                t += __shfl_xor(t, msk, 64);
            lrow[r] = lrow[r] * alpha[r] + t;
        }
        {   // rescale O by alpha (component j of f32x4 == reg j == q-row)
            f32x4 av; av[0] = alpha[0]; av[1] = alpha[1]; av[2] = alpha[2]; av[3] = alpha[3];
            #pragma unroll
            for (int dt = 0; dt < 4; ++dt) oacc[dt] *= av;
        }

        // ---- P -> per-wave LDS (bf16), then read back as A-fragments ----
        unsigned short* pw = &Pl[w][0];
        #pragma unroll
        for (int nt = 0; nt < 4; ++nt) {
            const int cc = nt * 16 + l15;
            #pragma unroll
            for (int r = 0; r < 4; ++r)
                pw[(lg * 4 + r) * PT_STRIDE + cc] = (unsigned short)f2bf(sacc[nt][r]);
        }
        // (same-wave LDS RAW: compiler inserts lgkmcnt)

        // ---- PV: O[16 q][64 d] += P[16][64] * V[64][64] ----
        #pragma unroll
        for (int s2 = 0; s2 < 2; ++s2) {
            bf16x8 pf = *(const bf16x8*)(pw + l15 * PT_STRIDE + s2 * 32 + lg * 8);
            #pragma unroll
            for (int dt = 0; dt < 4; ++dt) {
                const int d = dt * 16 + l15;   // B col = d
                bf16x8 vf = *(const bf16x8*)(Vt + ((d * 64 + s2 * 32 + lg * 8)
                                                   ^ ((((d & 7) ^ ((d >> 3) & 7))) << 3)));
                oacc[dt] = __builtin_amdgcn_mfma_f32_16x16x32_bf16(pf, vf, oacc[dt], 0, 0, 0);
            }
        }
    }

    // ---- epilogue: divide by l, store bf16 ----
    float inv[4];
    #pragma unroll
    for (int r = 0; r < 4; ++r) inv[r] = 1.f / lrow[r];
    unsigned short* ob = O + (size_t)(head * Sq + q0 + w * 16) * Dq;
    #pragma unroll
    for (int dt = 0; dt < 4; ++dt) {
        #pragma unroll
        for (int r = 0; r < 4; ++r) {
            const int row = lg * 4 + r;
            ob[(size_t)row * Dq + dt * 16 + l15] = (unsigned short)f2bf(oacc[dt][r] * inv[r]);
        }
    }
}

// ---------- fp32 fallback: one thread per query row (previous working path) ----------
__device__ __forceinline__ void fa_f32(const float* Q, const float* K,
                                       const float* V, float* O, int row) {
    const int head = row >> 11;
    const size_t hb = (size_t)head * Sq * Dq;

    float qf[Dq];
    {
        const float4* qp = (const float4*)(Q + (size_t)row * Dq);
        #pragma unroll
        for (int c = 0; c < Dq / 4; ++c) {
            float4 u = qp[c];
            qf[c*4+0]=u.x; qf[c*4+1]=u.y; qf[c*4+2]=u.z; qf[c*4+3]=u.w;
        }
    }
    float o[Dq];
    #pragma unroll
    for (int d = 0; d < Dq; ++d) o[d] = 0.f;
    float m = -1e30f, l = 0.f;

    const float4* kp = (const float4*)(K + hb);
    const float4* vp = (const float4*)(V + hb);

    for (int j = 0; j < Sq; ++j) {
        float s = 0.f;
        #pragma unroll
        for (int c = 0; c < Dq / 4; ++c) {
            float4 u = kp[j * (Dq/4) + c];
            s += qf[c*4+0]*u.x + qf[c*4+1]*u.y + qf[c*4+2]*u.z + qf[c*4+3]*u.w;
        }
        s *= 0.125f;
        if (s > m) {
            float alpha = __expf(m - s);
            l *= alpha;
            #pragma unroll
            for (int d = 0; d < Dq; ++d) o[d] *= alpha;
            m = s;
        }
        float p = __expf(s - m);
        l += p;
        #pragma unroll
        for (int c = 0; c < Dq / 4; ++c) {
            float4 u = vp[j * (Dq/4) + c];
            o[c*4+0]+=p*u.x; o[c*4+1]+=p*u.y; o[c*4+2]+=p*u.z; o[c*4+3]+=p*u.w;
        }
    }
    const float invl = 1.f / l;
    float4* op = (float4*)(O + (size_t)row * Dq);
    #pragma unroll
    for (int c = 0; c < Dq / 4; ++c) {
        float4 u;
        u.x=o[c*4+0]*invl; u.y=o[c*4+1]*invl; u.z=o[c*4+2]*invl; u.w=o[c*4+3]*invl;
        op[c] = u;
    }
}

__global__ __launch_bounds__(256, 2) void fa_f32_fallback(
    const void* __restrict__ Q, const void* __restrict__ K,
    const void* __restrict__ V, void* __restrict__ O,
    const int* __restrict__ flag)
{
    if (*flag) return;   // bf16 data -> MFMA kernel handles it
    const int row = blockIdx.x * 256 + threadIdx.x;
    fa_f32((const float*)Q, (const float*)K, (const float*)V, (float*)O, row);
}

extern "C" void kernel_launch(void* const* d_in, const int* in_sizes, int n_in,
                              void* d_out, int out_size, void* d_ws, size_t ws_size,
                              hipStream_t stream) {
    int* flag = (int*)d_ws;
    detect_dtype<<<dim3(1), dim3(64), 0, stream>>>((const unsigned int*)d_in[0], flag);
    fa_mfma<<<dim3(NBLK), dim3(256), 0, stream>>>(
        (const unsigned short*)d_in[0], (const unsigned short*)d_in[1],
        (const unsigned short*)d_in[2], (unsigned short*)d_out, flag);
    fa_f32_fallback<<<dim3(NROWS / 256), dim3(256), 0, stream>>>(
        d_in[0], d_in[1], d_in[2], d_out, flag);
}

// Round 2
// 415.382 us; speedup vs baseline: 13.0465x; 13.0465x over previous
//
#include <hip/hip_runtime.h>

#define Sq 2048
#define Dq 64
#define NH 64                    // B*H heads
#define QBLK 64                  // Q rows per block (4 waves x 16)
#define KVBLK 64                 // KV rows per iteration
#define NKVIT (Sq / KVBLK)       // 32
#define NQB (Sq / QBLK)          // 32 q-blocks per head
#define NBLK (NH * NQB)          // 2048 blocks
#define PT_STRIDE 72             // P lds row stride (bf16 elems): 144B, conflict-spread reads

typedef __attribute__((ext_vector_type(8))) short bf16x8;   // 8 bf16 = 4 VGPR
typedef __attribute__((ext_vector_type(4))) float f32x4;    // MFMA acc

// ---------- bf16 helpers ----------
__device__ __forceinline__ float bflo(unsigned int u) {
    union { unsigned int i; float f; } x; x.i = u << 16; return x.f;
}
__device__ __forceinline__ unsigned int f2bf(float f) {
    union { float f; unsigned int i; } x; x.f = f;
    return (x.i + 0x7fffu + ((x.i >> 16) & 1u)) >> 16;   // RNE
}

// ---------- dtype detector (deterministic; measured flag=0 on this data) ----------
__global__ void detect_dtype(const unsigned int* __restrict__ Q,
                             int* __restrict__ flag) {
    unsigned int u = Q[threadIdx.x];
    float a = fabsf(bflo(u));
    bool sane = (a >= 9.3e-10f) && (a <= 64.0f);
    unsigned long long b = __ballot(sane);
    if (threadIdx.x == 0) *flag = (__builtin_popcountll(b) >= 48) ? 1 : 0;
}

// ---------- async global->LDS, 16B per lane (bf16 path only) ----------
__device__ __forceinline__ void gload_lds16(const unsigned short* g, unsigned short* l) {
    __builtin_amdgcn_global_load_lds(
        (const __attribute__((address_space(1))) void*)g,
        (__attribute__((address_space(3))) void*)l, 16, 0, 0);
}

// Vt (= V^T [d][kv]) element index with XOR swizzle (write & read use the same map).
__device__ __forceinline__ int vt_swz(int d, int kv) {
    return (d * KVBLK + kv) ^ ((((d & 7) ^ ((d >> 3) & 7))) << 3);
}

// =====================================================================
// fp32-input MFMA flash attention (the real data path)
// =====================================================================
__global__ __launch_bounds__(256, 2) void fa_mfma_f32(
    const float* __restrict__ Q, const float* __restrict__ K,
    const float* __restrict__ V, float* __restrict__ O,
    const int* __restrict__ flag)
{
    if (*flag) return;   // bf16 data -> bf16 kernel handles it

    __shared__ __align__(16) unsigned short Kh[KVBLK * Dq];        // 8 KiB, hi bf16, swizzled
    __shared__ __align__(16) unsigned short Kl[KVBLK * Dq];        // 8 KiB, lo bf16, swizzled
    __shared__ __align__(16) unsigned short Vt[Dq * KVBLK];        // 8 KiB, V^T bf16, swizzled
    __shared__ __align__(16) unsigned short Pl[4][16 * PT_STRIDE]; // 9 KiB, per-wave P

    const int tid  = threadIdx.x;
    const int lane = tid & 63;
    const int w    = tid >> 6;       // wave 0..3
    const int l15  = lane & 15;
    const int lg   = lane >> 4;      // 0..3

    // XCD-aware bijective swizzle: 2048 blocks = 8 XCDs x 256.
    const int bid  = (int)blockIdx.x;
    const int blk  = (bid & 7) * (NBLK / 8) + (bid >> 3);
    const int head = blk >> 5;
    const int q0   = (blk & 31) * QBLK;
    const size_t hb = (size_t)head * (Sq * Dq);

    // ---- Q fragments: pre-scaled by 1/8, split into hi+lo bf16 ----
    // A-frag (16x16x32): lane holds A row (lane&15), k = (lane>>4)*8 + j (+32 per slice)
    bf16x8 qh[2], ql[2];
    {
        const float* qp = Q + hb + (size_t)(q0 + w * 16 + l15) * Dq + lg * 8;
        #pragma unroll
        for (int s = 0; s < 2; ++s) {
            #pragma unroll
            for (int j = 0; j < 8; ++j) {
                float x = qp[s * 32 + j] * 0.125f;
                unsigned int u = __float_as_uint(x);
                float hf = __uint_as_float(u & 0xffff0000u);
                qh[s][j] = (short)(u >> 16);
                ql[s][j] = (short)(__float_as_uint(x - hf) >> 16);
            }
        }
    }

    f32x4 oacc[4];
    #pragma unroll
    for (int dt = 0; dt < 4; ++dt) oacc[dt] = (f32x4){0.f, 0.f, 0.f, 0.f};
    float mrow[4], lrow[4];
    #pragma unroll
    for (int r = 0; r < 4; ++r) { mrow[r] = -1e30f; lrow[r] = 0.f; }

    const float* kbase = K + hb;
    const float* vbase = V + hb;

    // ---- prologue: load KV tile 0 into registers (flat-contiguous, coalesced) ----
    float4 kr[4], vr[4];
    {
        const float4* kt4 = (const float4*)kbase;
        const float4* vt4 = (const float4*)vbase;
        #pragma unroll
        for (int c = 0; c < 4; ++c) { kr[c] = kt4[c * 256 + tid]; vr[c] = vt4[c * 256 + tid]; }
    }

    for (int it = 0; it < NKVIT; ++it) {
        __syncthreads();   // all waves done reading previous tile's LDS

        // ---- convert + write K hi/lo into swizzled LDS ----
        #pragma unroll
        for (int c = 0; c < 4; ++c) {
            const int r  = c * 16 + (tid >> 4);          // kv row
            const int c0 = (tid & 15) * 4;               // d col base
            const int sw = c0 ^ ((r & 7) << 3);          // read-side XOR swizzle
            float xs[4] = {kr[c].x, kr[c].y, kr[c].z, kr[c].w};
            unsigned int hp[2], lp[2];
            #pragma unroll
            for (int e = 0; e < 2; ++e) {
                unsigned int u0 = __float_as_uint(xs[2*e]);
                unsigned int u1 = __float_as_uint(xs[2*e+1]);
                hp[e] = (u0 >> 16) | (u1 & 0xffff0000u);
                float h0 = __uint_as_float(u0 & 0xffff0000u);
                float h1 = __uint_as_float(u1 & 0xffff0000u);
                lp[e] = (__float_as_uint(xs[2*e] - h0) >> 16)
                      | (__float_as_uint(xs[2*e+1] - h1) & 0xffff0000u);
            }
            *(uint2*)(Kh + r * 64 + sw) = make_uint2(hp[0], hp[1]);
            *(uint2*)(Kl + r * 64 + sw) = make_uint2(lp[0], lp[1]);
        }
        // ---- convert + transpose-write V into Vt (RNE bf16) ----
        #pragma unroll
        for (int c = 0; c < 4; ++c) {
            const int kv = c * 16 + (tid >> 4);
            const int d0 = (tid & 15) * 4;
            float xs[4] = {vr[c].x, vr[c].y, vr[c].z, vr[c].w};
            #pragma unroll
            for (int e = 0; e < 4; ++e)
                Vt[vt_swz(d0 + e, kv)] = (unsigned short)f2bf(xs[e]);
        }

        __syncthreads();   // tile visible to all waves

        // ---- prefetch next KV tile into registers (hides latency under compute) ----
        if (it + 1 < NKVIT) {
            const float4* kt4 = (const float4*)(kbase + (size_t)(it + 1) * KVBLK * Dq);
            const float4* vt4 = (const float4*)(vbase + (size_t)(it + 1) * KVBLK * Dq);
            #pragma unroll
            for (int c = 0; c < 4; ++c) { kr[c] = kt4[c * 256 + tid]; vr[c] = vt4[c * 256 + tid]; }
        }

        // ---- QK^T with hi/lo split: S = Qh Kh + Qh Kl + Ql Kh ----
        f32x4 sacc[4];
        #pragma unroll
        for (int nt = 0; nt < 4; ++nt) sacc[nt] = (f32x4){0.f, 0.f, 0.f, 0.f};
        #pragma unroll
        for (int s = 0; s < 2; ++s) {
            #pragma unroll
            for (int nt = 0; nt < 4; ++nt) {
                const int n = nt * 16 + l15;                      // kv row = B col
                const int off = n * 64 + ((s * 32 + lg * 8) ^ ((n & 7) << 3));
                bf16x8 khf = *(const bf16x8*)(Kh + off);
                bf16x8 klf = *(const bf16x8*)(Kl + off);
                sacc[nt] = __builtin_amdgcn_mfma_f32_16x16x32_bf16(qh[s], khf, sacc[nt], 0, 0, 0);
                sacc[nt] = __builtin_amdgcn_mfma_f32_16x16x32_bf16(qh[s], klf, sacc[nt], 0, 0, 0);
                sacc[nt] = __builtin_amdgcn_mfma_f32_16x16x32_bf16(ql[s], khf, sacc[nt], 0, 0, 0);
            }
        }

        // ---- online softmax (q-row r in 16-lane group, reg r) ----
        float mnew[4], alpha[4];
        #pragma unroll
        for (int r = 0; r < 4; ++r) {
            float t = fmaxf(fmaxf(sacc[0][r], sacc[1][r]), fmaxf(sacc[2][r], sacc[3][r]));
            #pragma unroll
            for (int msk = 1; msk <= 8; msk <<= 1)
                t = fmaxf(t, __shfl_xor(t, msk, 64));
            mnew[r]  = fmaxf(mrow[r], t);
            alpha[r] = __expf(mrow[r] - mnew[r]);
            mrow[r]  = mnew[r];
        }
        float psum[4] = {0.f, 0.f, 0.f, 0.f};
        #pragma unroll
        for (int nt = 0; nt < 4; ++nt) {
            #pragma unroll
            for (int r = 0; r < 4; ++r) {
                float p = __expf(sacc[nt][r] - mnew[r]);
                sacc[nt][r] = p;
                psum[r] += p;
            }
        }
        #pragma unroll
        for (int r = 0; r < 4; ++r) {
            float t = psum[r];
            #pragma unroll
            for (int msk = 1; msk <= 8; msk <<= 1)
                t += __shfl_xor(t, msk, 64);
            lrow[r] = lrow[r] * alpha[r] + t;
        }
        {
            f32x4 av; av[0] = alpha[0]; av[1] = alpha[1]; av[2] = alpha[2]; av[3] = alpha[3];
            #pragma unroll
            for (int dt = 0; dt < 4; ++dt) oacc[dt] *= av;
        }

        // ---- P -> per-wave LDS (RNE bf16), read back as A-fragments ----
        unsigned short* pw = &Pl[w][0];
        #pragma unroll
        for (int nt = 0; nt < 4; ++nt) {
            const int cc = nt * 16 + l15;
            #pragma unroll
            for (int r = 0; r < 4; ++r)
                pw[(lg * 4 + r) * PT_STRIDE + cc] = (unsigned short)f2bf(sacc[nt][r]);
        }

        // ---- PV: O[16 q][64 d] += P[16][64] * V[64][64] ----
        #pragma unroll
        for (int s2 = 0; s2 < 2; ++s2) {
            bf16x8 pf = *(const bf16x8*)(pw + l15 * PT_STRIDE + s2 * 32 + lg * 8);
            #pragma unroll
            for (int dt = 0; dt < 4; ++dt) {
                const int d = dt * 16 + l15;
                bf16x8 vf = *(const bf16x8*)(Vt + ((d * 64 + s2 * 32 + lg * 8)
                                                   ^ ((((d & 7) ^ ((d >> 3) & 7))) << 3)));
                oacc[dt] = __builtin_amdgcn_mfma_f32_16x16x32_bf16(pf, vf, oacc[dt], 0, 0, 0);
            }
        }
    }

    // ---- epilogue: divide by l, store fp32 ----
    float inv4[4];
    #pragma unroll
    for (int r = 0; r < 4; ++r) inv4[r] = 1.f / lrow[r];
    float* ob = O + hb + (size_t)(q0 + w * 16) * Dq;
    #pragma unroll
    for (int dt = 0; dt < 4; ++dt) {
        #pragma unroll
        for (int r = 0; r < 4; ++r)
            ob[(size_t)(lg * 4 + r) * Dq + dt * 16 + l15] = oacc[dt][r] * inv4[r];
    }
}

// =====================================================================
// bf16-input MFMA flash attention (kept for flag=1 robustness; unchanged r1)
// =====================================================================
__global__ __launch_bounds__(256, 3) void fa_mfma_bf16(
    const unsigned short* __restrict__ Q, const unsigned short* __restrict__ K,
    const unsigned short* __restrict__ V, unsigned short* __restrict__ O,
    const int* __restrict__ flag)
{
    if (!(*flag)) return;

    __shared__ __align__(16) unsigned short Kt[KVBLK * Dq];
    __shared__ __align__(16) unsigned short Vt[Dq * KVBLK];
    __shared__ __align__(16) unsigned short Pl[4][16 * PT_STRIDE];

    const int tid  = threadIdx.x;
    const int lane = tid & 63;
    const int w    = tid >> 6;
    const int l15  = lane & 15;
    const int lg   = lane >> 4;

    const int bid  = (int)blockIdx.x;
    const int blk  = (bid & 7) * (NBLK / 8) + (bid >> 3);
    const int head = blk >> 5;
    const int q0   = (blk & 31) * QBLK;
    const size_t hb = (size_t)head * (Sq * Dq);

    bf16x8 qf[2];
    {
        const bf16x8* qp = (const bf16x8*)(Q + hb + (size_t)(q0 + w * 16 + l15) * Dq);
        qf[0] = qp[lg];
        qf[1] = qp[4 + lg];
    }

    f32x4 oacc[4];
    #pragma unroll
    for (int dt = 0; dt < 4; ++dt) oacc[dt] = (f32x4){0.f, 0.f, 0.f, 0.f};
    float mrow[4], lrow[4];
    #pragma unroll
    for (int r = 0; r < 4; ++r) { mrow[r] = -1e30f; lrow[r] = 0.f; }

    const int sr = tid >> 3;
    const int sc = tid & 7;
    const int kswz_elem = (sc * 8) ^ ((sr & 7) << 3);

    for (int it = 0; it < NKVIT; ++it) {
        const int kv0 = it * KVBLK;
        __syncthreads();
        #pragma unroll
        for (int c = 0; c < 2; ++c) {
            gload_lds16(K + hb + (size_t)(kv0 + c * 32 + sr) * Dq + kswz_elem,
                        Kt + c * 2048 + tid * 8);
        }
        uint4 vreg[2];
        #pragma unroll
        for (int c = 0; c < 2; ++c)
            vreg[c] = *(const uint4*)(V + hb + (size_t)(kv0 + c * 32 + sr) * Dq + sc * 8);

        asm volatile("s_waitcnt vmcnt(0)" ::: "memory");

        #pragma unroll
        for (int c = 0; c < 2; ++c) {
            const int kv = c * 32 + sr;
            unsigned int vu[4] = { vreg[c].x, vreg[c].y, vreg[c].z, vreg[c].w };
            #pragma unroll
            for (int e2 = 0; e2 < 4; ++e2) {
                const int d0 = sc * 8 + e2 * 2;
                Vt[vt_swz(d0,     kv)] = (unsigned short)(vu[e2] & 0xffffu);
                Vt[vt_swz(d0 + 1, kv)] = (unsigned short)(vu[e2] >> 16);
            }
        }
        __syncthreads();

        f32x4 sacc[4];
        #pragma unroll
        for (int nt = 0; nt < 4; ++nt) sacc[nt] = (f32x4){0.f, 0.f, 0.f, 0.f};
        #pragma unroll
        for (int s = 0; s < 2; ++s) {
            #pragma unroll
            for (int nt = 0; nt < 4; ++nt) {
                const int n = nt * 16 + l15;
                bf16x8 kf = *(const bf16x8*)(Kt + n * 64 + ((s * 32 + lg * 8) ^ ((n & 7) << 3)));
                sacc[nt] = __builtin_amdgcn_mfma_f32_16x16x32_bf16(qf[s], kf, sacc[nt], 0, 0, 0);
            }
        }
        #pragma unroll
        for (int nt = 0; nt < 4; ++nt) sacc[nt] *= 0.125f;

        float mnew[4], alpha[4];
        #pragma unroll
        for (int r = 0; r < 4; ++r) {
            float t = fmaxf(fmaxf(sacc[0][r], sacc[1][r]), fmaxf(sacc[2][r], sacc[3][r]));
            #pragma unroll
            for (int msk = 1; msk <= 8; msk <<= 1)
                t = fmaxf(t, __shfl_xor(t, msk, 64));
            mnew[r]  = fmaxf(mrow[r], t);
            alpha[r] = __expf(mrow[r] - mnew[r]);
            mrow[r]  = mnew[r];
        }
        float psum[4] = {0.f, 0.f, 0.f, 0.f};
        #pragma unroll
        for (int nt = 0; nt < 4; ++nt) {
            #pragma unroll
            for (int r = 0; r < 4; ++r) {
                float p = __expf(sacc[nt][r] - mnew[r]);
                sacc[nt][r] = p;
                psum[r] += p;
            }
        }
        #pragma unroll
        for (int r = 0; r < 4; ++r) {
            float t = psum[r];
            #pragma unroll
            for (int msk = 1; msk <= 8; msk <<= 1)
                t += __shfl_xor(t, msk, 64);
            lrow[r] = lrow[r] * alpha[r] + t;
        }
        {
            f32x4 av; av[0] = alpha[0]; av[1] = alpha[1]; av[2] = alpha[2]; av[3] = alpha[3];
            #pragma unroll
            for (int dt = 0; dt < 4; ++dt) oacc[dt] *= av;
        }

        unsigned short* pw = &Pl[w][0];
        #pragma unroll
        for (int nt = 0; nt < 4; ++nt) {
            const int cc = nt * 16 + l15;
            #pragma unroll
            for (int r = 0; r < 4; ++r)
                pw[(lg * 4 + r) * PT_STRIDE + cc] = (unsigned short)f2bf(sacc[nt][r]);
        }

        #pragma unroll
        for (int s2 = 0; s2 < 2; ++s2) {
            bf16x8 pf = *(const bf16x8*)(pw + l15 * PT_STRIDE + s2 * 32 + lg * 8);
            #pragma unroll
            for (int dt = 0; dt < 4; ++dt) {
                const int d = dt * 16 + l15;
                bf16x8 vf = *(const bf16x8*)(Vt + ((d * 64 + s2 * 32 + lg * 8)
                                                   ^ ((((d & 7) ^ ((d >> 3) & 7))) << 3)));
                oacc[dt] = __builtin_amdgcn_mfma_f32_16x16x32_bf16(pf, vf, oacc[dt], 0, 0, 0);
            }
        }
    }

    float inv4[4];
    #pragma unroll
    for (int r = 0; r < 4; ++r) inv4[r] = 1.f / lrow[r];
    unsigned short* ob = O + (size_t)(head * Sq + q0 + w * 16) * Dq;
    #pragma unroll
    for (int dt = 0; dt < 4; ++dt) {
        #pragma unroll
        for (int r = 0; r < 4; ++r)
            ob[(size_t)(lg * 4 + r) * Dq + dt * 16 + l15] = (unsigned short)f2bf(oacc[dt][r] * inv4[r]);
    }
}

extern "C" void kernel_launch(void* const* d_in, const int* in_sizes, int n_in,
                              void* d_out, int out_size, void* d_ws, size_t ws_size,
                              hipStream_t stream) {
    int* flag = (int*)d_ws;
    detect_dtype<<<dim3(1), dim3(64), 0, stream>>>((const unsigned int*)d_in[0], flag);
    fa_mfma_f32<<<dim3(NBLK), dim3(256), 0, stream>>>(
        (const float*)d_in[0], (const float*)d_in[1],
        (const float*)d_in[2], (float*)d_out, flag);
    fa_mfma_bf16<<<dim3(NBLK), dim3(256), 0, stream>>>(
        (const unsigned short*)d_in[0], (const unsigned short*)d_in[1],
        (const unsigned short*)d_in[2], (unsigned short*)d_out, flag);
}

// Round 3
// 390.946 us; speedup vs baseline: 13.8620x; 1.0625x over previous
//
#include <hip/hip_runtime.h>

#define Sq 2048
#define Dq 64
#define NH 64                    // B*H heads
#define QBLK 64                  // Q rows per block (4 waves x 16)
#define KVBLK 64                 // KV rows per iteration
#define NKVIT (Sq / KVBLK)       // 32
#define NQB (Sq / QBLK)          // 32 q-blocks per head
#define NBLK (NH * NQB)          // 2048 blocks
#define PT_STRIDE 72             // P lds row stride (bf16 elems)

#define TILE_ELEMS 4096          // 64x64 bf16 per tile image
#define IMG_TILES (NH * NKVIT)   // 2048 tiles per image
#define IMG_BYTES ((size_t)IMG_TILES * TILE_ELEMS * 2)   // 16,777,216 B
#define WS_IMG_OFF 4096
#define WS_NEEDED (WS_IMG_OFF + 3 * IMG_BYTES)           // ~50.3 MB

#define QK_SCALE (0.125f * 1.44269504088896f)  // 1/sqrt(D) * log2(e): softmax in exp2 domain
#define DEFER_THR 8.0f                          // T13: P bounded by 2^8

typedef __attribute__((ext_vector_type(8))) short bf16x8;   // 8 bf16 = 4 VGPR
typedef __attribute__((ext_vector_type(4))) float f32x4;    // MFMA acc

// ---------- bf16 helpers ----------
__device__ __forceinline__ float bflo(unsigned int u) {
    union { unsigned int i; float f; } x; x.i = u << 16; return x.f;
}
__device__ __forceinline__ unsigned int f2bf(float f) {
    union { float f; unsigned int i; } x; x.f = f;
    return (x.i + 0x7fffu + ((x.i >> 16) & 1u)) >> 16;   // RNE
}

// ---------- dtype detector (deterministic; measured flag=0 on this data) ----------
__global__ void detect_dtype(const unsigned int* __restrict__ Q,
                             int* __restrict__ flag) {
    unsigned int u = Q[threadIdx.x];
    float a = fabsf(bflo(u));
    bool sane = (a >= 9.3e-10f) && (a <= 64.0f);
    unsigned long long b = __ballot(sane);
    if (threadIdx.x == 0) *flag = (__builtin_popcountll(b) >= 48) ? 1 : 0;
}

// ---------- async global->LDS, 16B per lane ----------
__device__ __forceinline__ void gload_lds16(const unsigned short* g, unsigned short* l) {
    __builtin_amdgcn_global_load_lds(
        (const __attribute__((address_space(1))) void*)g,
        (__attribute__((address_space(3))) void*)l, 16, 0, 0);
}

// Vt (= V^T [d][kv]) element index with XOR swizzle (write & read use the same map).
__device__ __forceinline__ int vt_swz(int d, int kv) {
    return (d * KVBLK + kv) ^ ((((d & 7) ^ ((d >> 3) & 7))) << 3);
}

// =====================================================================
// Pre-pass: convert K -> (Khi,Klo) bf16 split, V -> V^T bf16, each 64x64
// tile stored in workspace in the EXACT swizzled LDS-image order.
// One block per (head,tile). Memory-bound, ~20us total.
// =====================================================================
__global__ __launch_bounds__(256) void convert_kv(
    const float* __restrict__ K, const float* __restrict__ V,
    unsigned short* __restrict__ img, const int* __restrict__ flag)
{
    if (*flag) return;   // bf16 input -> images unused
    __shared__ __align__(16) unsigned short VtL[TILE_ELEMS];

    const int tile = (int)blockIdx.x;            // head*32 + it (tiles contiguous)
    const int tid  = threadIdx.x;
    const size_t gbase = (size_t)tile * (KVBLK * Dq);   // floats

    unsigned short* khi = img + (size_t)tile * TILE_ELEMS;
    unsigned short* klo = img + (size_t)(IMG_TILES + tile) * TILE_ELEMS;
    unsigned short* vtg = img + (size_t)(2 * IMG_TILES + tile) * TILE_ELEMS;

    const float4* kt4 = (const float4*)(K + gbase);
    const float4* vt4 = (const float4*)(V + gbase);

    #pragma unroll
    for (int c = 0; c < 4; ++c) {
        const int r  = (c * 256 + tid) >> 4;     // row 0..63
        const int c0 = (tid & 15) * 4;           // col base
        // ---- K: hi/lo bf16 split, swizzled row layout ----
        {
            float4 u4 = kt4[c * 256 + tid];
            float xs[4] = {u4.x, u4.y, u4.z, u4.w};
            unsigned int hp[2], lp[2];
            #pragma unroll
            for (int e = 0; e < 2; ++e) {
                unsigned int u0 = __float_as_uint(xs[2*e]);
                unsigned int u1 = __float_as_uint(xs[2*e+1]);
                hp[e] = (u0 >> 16) | (u1 & 0xffff0000u);
                float h0 = __uint_as_float(u0 & 0xffff0000u);
                float h1 = __uint_as_float(u1 & 0xffff0000u);
                lp[e] = (__float_as_uint(xs[2*e] - h0) >> 16)
                      | (__float_as_uint(xs[2*e+1] - h1) & 0xffff0000u);
            }
            const int sw = c0 ^ ((r & 7) << 3);
            *(uint2*)(khi + r * 64 + sw) = make_uint2(hp[0], hp[1]);
            *(uint2*)(klo + r * 64 + sw) = make_uint2(lp[0], lp[1]);
        }
        // ---- V: RNE bf16, transposed+swizzled via LDS ----
        {
            float4 u4 = vt4[c * 256 + tid];
            float xs[4] = {u4.x, u4.y, u4.z, u4.w};
            #pragma unroll
            for (int e = 0; e < 4; ++e)
                VtL[vt_swz(c0 + e, r)] = (unsigned short)f2bf(xs[e]);
        }
    }
    __syncthreads();
    #pragma unroll
    for (int c = 0; c < 2; ++c)
        *(uint4*)(vtg + (c * 256 + tid) * 8) = *(const uint4*)(VtL + (c * 256 + tid) * 8);
}

// =====================================================================
// Main fp32-input MFMA flash attention, staging pre-converted tile images
// =====================================================================
__global__ __launch_bounds__(256, 4) void fa_mfma_f32_pre(
    const float* __restrict__ Q, const unsigned short* __restrict__ img,
    float* __restrict__ O, const int* __restrict__ flag)
{
    if (*flag) return;

    __shared__ __align__(16) unsigned short Kh[TILE_ELEMS];        // 8 KiB
    __shared__ __align__(16) unsigned short Kl[TILE_ELEMS];        // 8 KiB
    __shared__ __align__(16) unsigned short Vt[TILE_ELEMS];        // 8 KiB
    __shared__ __align__(16) unsigned short Pl[4][16 * PT_STRIDE]; // 9 KiB

    const int tid  = threadIdx.x;
    const int lane = tid & 63;
    const int w    = tid >> 6;
    const int l15  = lane & 15;
    const int lg   = lane >> 4;

    // XCD-aware bijective swizzle: 2048 blocks = 8 XCDs x 256
    const int bid  = (int)blockIdx.x;
    const int blk  = (bid & 7) * (NBLK / 8) + (bid >> 3);
    const int head = blk >> 5;
    const int q0   = (blk & 31) * QBLK;
    const size_t hb = (size_t)head * (Sq * Dq);

    // ---- Q fragments: scaled by 1/8*log2e, hi/lo bf16 split ----
    bf16x8 qh[2], ql[2];
    {
        const float4* qv = (const float4*)(Q + hb + (size_t)(q0 + w * 16 + l15) * Dq + lg * 8);
        #pragma unroll
        for (int s = 0; s < 2; ++s) {
            float xs[8];
            #pragma unroll
            for (int j4 = 0; j4 < 2; ++j4) {
                float4 u = qv[s * 8 + j4];
                xs[j4*4+0]=u.x; xs[j4*4+1]=u.y; xs[j4*4+2]=u.z; xs[j4*4+3]=u.w;
            }
            #pragma unroll
            for (int j = 0; j < 8; ++j) {
                float x = xs[j] * QK_SCALE;
                unsigned int u = __float_as_uint(x);
                float hf = __uint_as_float(u & 0xffff0000u);
                qh[s][j] = (short)(u >> 16);
                ql[s][j] = (short)(__float_as_uint(x - hf) >> 16);
            }
        }
    }

    f32x4 oacc[4];
    #pragma unroll
    for (int dt = 0; dt < 4; ++dt) oacc[dt] = (f32x4){0.f, 0.f, 0.f, 0.f};
    float mrow[4], lrow[4];
    #pragma unroll
    for (int r = 0; r < 4; ++r) { mrow[r] = -1e30f; lrow[r] = 0.f; }

    const unsigned short* khi_h = img + (size_t)(head * NKVIT) * TILE_ELEMS;
    const unsigned short* klo_h = img + (size_t)(IMG_TILES + head * NKVIT) * TILE_ELEMS;
    const unsigned short* vtg_h = img + (size_t)(2 * IMG_TILES + head * NKVIT) * TILE_ELEMS;

    for (int it = 0; it < NKVIT; ++it) {
        __syncthreads();   // all waves done reading previous tile

        // ---- stage tile images (linear copies, zero VALU conversion) ----
        const size_t toff = (size_t)it * TILE_ELEMS;
        #pragma unroll
        for (int c = 0; c < 2; ++c) {
            const int e8 = (c * 256 + tid) * 8;
            gload_lds16(khi_h + toff + e8, Kh + e8);
            gload_lds16(klo_h + toff + e8, Kl + e8);
            gload_lds16(vtg_h + toff + e8, Vt + e8);
        }
        asm volatile("s_waitcnt vmcnt(0)" ::: "memory");
        __syncthreads();   // tile visible to all waves

        // ---- QK^T with hi/lo split: S = Qh Kh + Qh Kl + Ql Kh (log2 units) ----
        f32x4 sacc[4];
        #pragma unroll
        for (int nt = 0; nt < 4; ++nt) sacc[nt] = (f32x4){0.f, 0.f, 0.f, 0.f};
        #pragma unroll
        for (int s = 0; s < 2; ++s) {
            #pragma unroll
            for (int nt = 0; nt < 4; ++nt) {
                const int n = nt * 16 + l15;
                const int off = n * 64 + ((s * 32 + lg * 8) ^ ((n & 7) << 3));
                bf16x8 khf = *(const bf16x8*)(Kh + off);
                bf16x8 klf = *(const bf16x8*)(Kl + off);
                sacc[nt] = __builtin_amdgcn_mfma_f32_16x16x32_bf16(qh[s], khf, sacc[nt], 0, 0, 0);
                sacc[nt] = __builtin_amdgcn_mfma_f32_16x16x32_bf16(qh[s], klf, sacc[nt], 0, 0, 0);
                sacc[nt] = __builtin_amdgcn_mfma_f32_16x16x32_bf16(ql[s], khf, sacc[nt], 0, 0, 0);
            }
        }

        // ---- online softmax, exp2 domain, defer-max (T13) ----
        float pmax[4];
        #pragma unroll
        for (int r = 0; r < 4; ++r) {
            float t = fmaxf(fmaxf(sacc[0][r], sacc[1][r]), fmaxf(sacc[2][r], sacc[3][r]));
            #pragma unroll
            for (int msk = 1; msk <= 8; msk <<= 1)
                t = fmaxf(t, __shfl_xor(t, msk, 64));
            pmax[r] = t;
        }
        bool grow = (pmax[0] > mrow[0] + DEFER_THR) | (pmax[1] > mrow[1] + DEFER_THR)
                  | (pmax[2] > mrow[2] + DEFER_THR) | (pmax[3] > mrow[3] + DEFER_THR);
        if (__any(grow)) {
            f32x4 av;
            #pragma unroll
            for (int r = 0; r < 4; ++r) {
                float mnew = fmaxf(mrow[r], pmax[r]);
                float alpha = exp2f(mrow[r] - mnew);
                mrow[r] = mnew;
                lrow[r] *= alpha;
                av[r] = alpha;
            }
            #pragma unroll
            for (int dt = 0; dt < 4; ++dt) oacc[dt] *= av;
        }
        float psum[4] = {0.f, 0.f, 0.f, 0.f};
        #pragma unroll
        for (int nt = 0; nt < 4; ++nt) {
            #pragma unroll
            for (int r = 0; r < 4; ++r) {
                float p = exp2f(sacc[nt][r] - mrow[r]);   // bounded by 2^8
                sacc[nt][r] = p;
                psum[r] += p;
            }
        }
        #pragma unroll
        for (int r = 0; r < 4; ++r) {
            float t = psum[r];
            #pragma unroll
            for (int msk = 1; msk <= 8; msk <<= 1)
                t += __shfl_xor(t, msk, 64);
            lrow[r] += t;
        }

        // ---- P -> per-wave LDS (RNE bf16), read back as A-fragments ----
        unsigned short* pw = &Pl[w][0];
        #pragma unroll
        for (int nt = 0; nt < 4; ++nt) {
            const int cc = nt * 16 + l15;
            #pragma unroll
            for (int r = 0; r < 4; ++r)
                pw[(lg * 4 + r) * PT_STRIDE + cc] = (unsigned short)f2bf(sacc[nt][r]);
        }

        // ---- PV: O[16 q][64 d] += P[16][64] * V[64][64] ----
        #pragma unroll
        for (int s2 = 0; s2 < 2; ++s2) {
            bf16x8 pf = *(const bf16x8*)(pw + l15 * PT_STRIDE + s2 * 32 + lg * 8);
            #pragma unroll
            for (int dt = 0; dt < 4; ++dt) {
                const int d = dt * 16 + l15;
                bf16x8 vf = *(const bf16x8*)(Vt + vt_swz(d, s2 * 32 + lg * 8));
                oacc[dt] = __builtin_amdgcn_mfma_f32_16x16x32_bf16(pf, vf, oacc[dt], 0, 0, 0);
            }
        }
    }

    // ---- epilogue ----
    float inv4[4];
    #pragma unroll
    for (int r = 0; r < 4; ++r) inv4[r] = 1.f / lrow[r];
    float* ob = O + hb + (size_t)(q0 + w * 16) * Dq;
    #pragma unroll
    for (int dt = 0; dt < 4; ++dt) {
        #pragma unroll
        for (int r = 0; r < 4; ++r)
            ob[(size_t)(lg * 4 + r) * Dq + dt * 16 + l15] = oacc[dt][r] * inv4[r];
    }
}

// =====================================================================
// Fallback fused fp32 kernel (round-2 version; used when ws too small)
// =====================================================================
__global__ __launch_bounds__(256, 2) void fa_mfma_f32_fused(
    const float* __restrict__ Q, const float* __restrict__ K,
    const float* __restrict__ V, float* __restrict__ O,
    const int* __restrict__ flag)
{
    if (*flag) return;

    __shared__ __align__(16) unsigned short Kh[KVBLK * Dq];
    __shared__ __align__(16) unsigned short Kl[KVBLK * Dq];
    __shared__ __align__(16) unsigned short Vt[Dq * KVBLK];
    __shared__ __align__(16) unsigned short Pl[4][16 * PT_STRIDE];

    const int tid  = threadIdx.x;
    const int lane = tid & 63;
    const int w    = tid >> 6;
    const int l15  = lane & 15;
    const int lg   = lane >> 4;

    const int bid  = (int)blockIdx.x;
    const int blk  = (bid & 7) * (NBLK / 8) + (bid >> 3);
    const int head = blk >> 5;
    const int q0   = (blk & 31) * QBLK;
    const size_t hb = (size_t)head * (Sq * Dq);

    bf16x8 qh[2], ql[2];
    {
        const float* qp = Q + hb + (size_t)(q0 + w * 16 + l15) * Dq + lg * 8;
        #pragma unroll
        for (int s = 0; s < 2; ++s) {
            #pragma unroll
            for (int j = 0; j < 8; ++j) {
                float x = qp[s * 32 + j] * 0.125f;
                unsigned int u = __float_as_uint(x);
                float hf = __uint_as_float(u & 0xffff0000u);
                qh[s][j] = (short)(u >> 16);
                ql[s][j] = (short)(__float_as_uint(x - hf) >> 16);
            }
        }
    }

    f32x4 oacc[4];
    #pragma unroll
    for (int dt = 0; dt < 4; ++dt) oacc[dt] = (f32x4){0.f, 0.f, 0.f, 0.f};
    float mrow[4], lrow[4];
    #pragma unroll
    for (int r = 0; r < 4; ++r) { mrow[r] = -1e30f; lrow[r] = 0.f; }

    const float* kbase = K + hb;
    const float* vbase = V + hb;

    float4 kr[4], vr[4];
    {
        const float4* kt4 = (const float4*)kbase;
        const float4* vt4 = (const float4*)vbase;
        #pragma unroll
        for (int c = 0; c < 4; ++c) { kr[c] = kt4[c * 256 + tid]; vr[c] = vt4[c * 256 + tid]; }
    }

    for (int it = 0; it < NKVIT; ++it) {
        __syncthreads();
        #pragma unroll
        for (int c = 0; c < 4; ++c) {
            const int r  = c * 16 + (tid >> 4);
            const int c0 = (tid & 15) * 4;
            const int sw = c0 ^ ((r & 7) << 3);
            float xs[4] = {kr[c].x, kr[c].y, kr[c].z, kr[c].w};
            unsigned int hp[2], lp[2];
            #pragma unroll
            for (int e = 0; e < 2; ++e) {
                unsigned int u0 = __float_as_uint(xs[2*e]);
                unsigned int u1 = __float_as_uint(xs[2*e+1]);
                hp[e] = (u0 >> 16) | (u1 & 0xffff0000u);
                float h0 = __uint_as_float(u0 & 0xffff0000u);
                float h1 = __uint_as_float(u1 & 0xffff0000u);
                lp[e] = (__float_as_uint(xs[2*e] - h0) >> 16)
                      | (__float_as_uint(xs[2*e+1] - h1) & 0xffff0000u);
            }
            *(uint2*)(Kh + r * 64 + sw) = make_uint2(hp[0], hp[1]);
            *(uint2*)(Kl + r * 64 + sw) = make_uint2(lp[0], lp[1]);
        }
        #pragma unroll
        for (int c = 0; c < 4; ++c) {
            const int kv = c * 16 + (tid >> 4);
            const int d0 = (tid & 15) * 4;
            float xs[4] = {vr[c].x, vr[c].y, vr[c].z, vr[c].w};
            #pragma unroll
            for (int e = 0; e < 4; ++e)
                Vt[vt_swz(d0 + e, kv)] = (unsigned short)f2bf(xs[e]);
        }
        __syncthreads();

        if (it + 1 < NKVIT) {
            const float4* kt4 = (const float4*)(kbase + (size_t)(it + 1) * KVBLK * Dq);
            const float4* vt4 = (const float4*)(vbase + (size_t)(it + 1) * KVBLK * Dq);
            #pragma unroll
            for (int c = 0; c < 4; ++c) { kr[c] = kt4[c * 256 + tid]; vr[c] = vt4[c * 256 + tid]; }
        }

        f32x4 sacc[4];
        #pragma unroll
        for (int nt = 0; nt < 4; ++nt) sacc[nt] = (f32x4){0.f, 0.f, 0.f, 0.f};
        #pragma unroll
        for (int s = 0; s < 2; ++s) {
            #pragma unroll
            for (int nt = 0; nt < 4; ++nt) {
                const int n = nt * 16 + l15;
                const int off = n * 64 + ((s * 32 + lg * 8) ^ ((n & 7) << 3));
                bf16x8 khf = *(const bf16x8*)(Kh + off);
                bf16x8 klf = *(const bf16x8*)(Kl + off);
                sacc[nt] = __builtin_amdgcn_mfma_f32_16x16x32_bf16(qh[s], khf, sacc[nt], 0, 0, 0);
                sacc[nt] = __builtin_amdgcn_mfma_f32_16x16x32_bf16(qh[s], klf, sacc[nt], 0, 0, 0);
                sacc[nt] = __builtin_amdgcn_mfma_f32_16x16x32_bf16(ql[s], khf, sacc[nt], 0, 0, 0);
            }
        }

        float mnew[4], alpha[4];
        #pragma unroll
        for (int r = 0; r < 4; ++r) {
            float t = fmaxf(fmaxf(sacc[0][r], sacc[1][r]), fmaxf(sacc[2][r], sacc[3][r]));
            #pragma unroll
            for (int msk = 1; msk <= 8; msk <<= 1)
                t = fmaxf(t, __shfl_xor(t, msk, 64));
            mnew[r]  = fmaxf(mrow[r], t);
            alpha[r] = __expf(mrow[r] - mnew[r]);
            mrow[r]  = mnew[r];
        }
        float psum[4] = {0.f, 0.f, 0.f, 0.f};
        #pragma unroll
        for (int nt = 0; nt < 4; ++nt) {
            #pragma unroll
            for (int r = 0; r < 4; ++r) {
                float p = __expf(sacc[nt][r] - mnew[r]);
                sacc[nt][r] = p;
                psum[r] += p;
            }
        }
        #pragma unroll
        for (int r = 0; r < 4; ++r) {
            float t = psum[r];
            #pragma unroll
            for (int msk = 1; msk <= 8; msk <<= 1)
                t += __shfl_xor(t, msk, 64);
            lrow[r] = lrow[r] * alpha[r] + t;
        }
        {
            f32x4 av; av[0] = alpha[0]; av[1] = alpha[1]; av[2] = alpha[2]; av[3] = alpha[3];
            #pragma unroll
            for (int dt = 0; dt < 4; ++dt) oacc[dt] *= av;
        }

        unsigned short* pw = &Pl[w][0];
        #pragma unroll
        for (int nt = 0; nt < 4; ++nt) {
            const int cc = nt * 16 + l15;
            #pragma unroll
            for (int r = 0; r < 4; ++r)
                pw[(lg * 4 + r) * PT_STRIDE + cc] = (unsigned short)f2bf(sacc[nt][r]);
        }

        #pragma unroll
        for (int s2 = 0; s2 < 2; ++s2) {
            bf16x8 pf = *(const bf16x8*)(pw + l15 * PT_STRIDE + s2 * 32 + lg * 8);
            #pragma unroll
            for (int dt = 0; dt < 4; ++dt) {
                const int d = dt * 16 + l15;
                bf16x8 vf = *(const bf16x8*)(Vt + vt_swz(d, s2 * 32 + lg * 8));
                oacc[dt] = __builtin_amdgcn_mfma_f32_16x16x32_bf16(pf, vf, oacc[dt], 0, 0, 0);
            }
        }
    }

    float inv4[4];
    #pragma unroll
    for (int r = 0; r < 4; ++r) inv4[r] = 1.f / lrow[r];
    float* ob = O + hb + (size_t)(q0 + w * 16) * Dq;
    #pragma unroll
    for (int dt = 0; dt < 4; ++dt) {
        #pragma unroll
        for (int r = 0; r < 4; ++r)
            ob[(size_t)(lg * 4 + r) * Dq + dt * 16 + l15] = oacc[dt][r] * inv4[r];
    }
}

// =====================================================================
// bf16-input MFMA flash attention (flag=1 robustness; unchanged)
// =====================================================================
__global__ __launch_bounds__(256, 3) void fa_mfma_bf16(
    const unsigned short* __restrict__ Q, const unsigned short* __restrict__ K,
    const unsigned short* __restrict__ V, unsigned short* __restrict__ O,
    const int* __restrict__ flag)
{
    if (!(*flag)) return;

    __shared__ __align__(16) unsigned short Kt[KVBLK * Dq];
    __shared__ __align__(16) unsigned short Vt[Dq * KVBLK];
    __shared__ __align__(16) unsigned short Pl[4][16 * PT_STRIDE];

    const int tid  = threadIdx.x;
    const int lane = tid & 63;
    const int w    = tid >> 6;
    const int l15  = lane & 15;
    const int lg   = lane >> 4;

    const int bid  = (int)blockIdx.x;
    const int blk  = (bid & 7) * (NBLK / 8) + (bid >> 3);
    const int head = blk >> 5;
    const int q0   = (blk & 31) * QBLK;
    const size_t hb = (size_t)head * (Sq * Dq);

    bf16x8 qf[2];
    {
        const bf16x8* qp = (const bf16x8*)(Q + hb + (size_t)(q0 + w * 16 + l15) * Dq);
        qf[0] = qp[lg];
        qf[1] = qp[4 + lg];
    }

    f32x4 oacc[4];
    #pragma unroll
    for (int dt = 0; dt < 4; ++dt) oacc[dt] = (f32x4){0.f, 0.f, 0.f, 0.f};
    float mrow[4], lrow[4];
    #pragma unroll
    for (int r = 0; r < 4; ++r) { mrow[r] = -1e30f; lrow[r] = 0.f; }

    const int sr = tid >> 3;
    const int sc = tid & 7;
    const int kswz_elem = (sc * 8) ^ ((sr & 7) << 3);

    for (int it = 0; it < NKVIT; ++it) {
        const int kv0 = it * KVBLK;
        __syncthreads();
        #pragma unroll
        for (int c = 0; c < 2; ++c) {
            gload_lds16(K + hb + (size_t)(kv0 + c * 32 + sr) * Dq + kswz_elem,
                        Kt + c * 2048 + tid * 8);
        }
        uint4 vreg[2];
        #pragma unroll
        for (int c = 0; c < 2; ++c)
            vreg[c] = *(const uint4*)(V + hb + (size_t)(kv0 + c * 32 + sr) * Dq + sc * 8);

        asm volatile("s_waitcnt vmcnt(0)" ::: "memory");

        #pragma unroll
        for (int c = 0; c < 2; ++c) {
            const int kv = c * 32 + sr;
            unsigned int vu[4] = { vreg[c].x, vreg[c].y, vreg[c].z, vreg[c].w };
            #pragma unroll
            for (int e2 = 0; e2 < 4; ++e2) {
                const int d0 = sc * 8 + e2 * 2;
                Vt[vt_swz(d0,     kv)] = (unsigned short)(vu[e2] & 0xffffu);
                Vt[vt_swz(d0 + 1, kv)] = (unsigned short)(vu[e2] >> 16);
            }
        }
        __syncthreads();

        f32x4 sacc[4];
        #pragma unroll
        for (int nt = 0; nt < 4; ++nt) sacc[nt] = (f32x4){0.f, 0.f, 0.f, 0.f};
        #pragma unroll
        for (int s = 0; s < 2; ++s) {
            #pragma unroll
            for (int nt = 0; nt < 4; ++nt) {
                const int n = nt * 16 + l15;
                bf16x8 kf = *(const bf16x8*)(Kt + n * 64 + ((s * 32 + lg * 8) ^ ((n & 7) << 3)));
                sacc[nt] = __builtin_amdgcn_mfma_f32_16x16x32_bf16(qf[s], kf, sacc[nt], 0, 0, 0);
            }
        }
        #pragma unroll
        for (int nt = 0; nt < 4; ++nt) sacc[nt] *= 0.125f;

        float mnew[4], alpha[4];
        #pragma unroll
        for (int r = 0; r < 4; ++r) {
            float t = fmaxf(fmaxf(sacc[0][r], sacc[1][r]), fmaxf(sacc[2][r], sacc[3][r]));
            #pragma unroll
            for (int msk = 1; msk <= 8; msk <<= 1)
                t = fmaxf(t, __shfl_xor(t, msk, 64));
            mnew[r]  = fmaxf(mrow[r], t);
            alpha[r] = __expf(mrow[r] - mnew[r]);
            mrow[r]  = mnew[r];
        }
        float psum[4] = {0.f, 0.f, 0.f, 0.f};
        #pragma unroll
        for (int nt = 0; nt < 4; ++nt) {
            #pragma unroll
            for (int r = 0; r < 4; ++r) {
                float p = __expf(sacc[nt][r] - mnew[r]);
                sacc[nt][r] = p;
                psum[r] += p;
            }
        }
        #pragma unroll
        for (int r = 0; r < 4; ++r) {
            float t = psum[r];
            #pragma unroll
            for (int msk = 1; msk <= 8; msk <<= 1)
                t += __shfl_xor(t, msk, 64);
            lrow[r] = lrow[r] * alpha[r] + t;
        }
        {
            f32x4 av; av[0] = alpha[0]; av[1] = alpha[1]; av[2] = alpha[2]; av[3] = alpha[3];
            #pragma unroll
            for (int dt = 0; dt < 4; ++dt) oacc[dt] *= av;
        }

        unsigned short* pw = &Pl[w][0];
        #pragma unroll
        for (int nt = 0; nt < 4; ++nt) {
            const int cc = nt * 16 + l15;
            #pragma unroll
            for (int r = 0; r < 4; ++r)
                pw[(lg * 4 + r) * PT_STRIDE + cc] = (unsigned short)f2bf(sacc[nt][r]);
        }

        #pragma unroll
        for (int s2 = 0; s2 < 2; ++s2) {
            bf16x8 pf = *(const bf16x8*)(pw + l15 * PT_STRIDE + s2 * 32 + lg * 8);
            #pragma unroll
            for (int dt = 0; dt < 4; ++dt) {
                const int d = dt * 16 + l15;
                bf16x8 vf = *(const bf16x8*)(Vt + vt_swz(d, s2 * 32 + lg * 8));
                oacc[dt] = __builtin_amdgcn_mfma_f32_16x16x32_bf16(pf, vf, oacc[dt], 0, 0, 0);
            }
        }
    }

    float inv4[4];
    #pragma unroll
    for (int r = 0; r < 4; ++r) inv4[r] = 1.f / lrow[r];
    unsigned short* ob = O + (size_t)(head * Sq + q0 + w * 16) * Dq;
    #pragma unroll
    for (int dt = 0; dt < 4; ++dt) {
        #pragma unroll
        for (int r = 0; r < 4; ++r)
            ob[(size_t)(lg * 4 + r) * Dq + dt * 16 + l15] = (unsigned short)f2bf(oacc[dt][r] * inv4[r]);
    }
}

extern "C" void kernel_launch(void* const* d_in, const int* in_sizes, int n_in,
                              void* d_out, int out_size, void* d_ws, size_t ws_size,
                              hipStream_t stream) {
    int* flag = (int*)d_ws;
    detect_dtype<<<dim3(1), dim3(64), 0, stream>>>((const unsigned int*)d_in[0], flag);
    if (ws_size >= WS_NEEDED) {
        unsigned short* img = (unsigned short*)((char*)d_ws + WS_IMG_OFF);
        convert_kv<<<dim3(IMG_TILES), dim3(256), 0, stream>>>(
            (const float*)d_in[1], (const float*)d_in[2], img, flag);
        fa_mfma_f32_pre<<<dim3(NBLK), dim3(256), 0, stream>>>(
            (const float*)d_in[0], img, (float*)d_out, flag);
    } else {
        fa_mfma_f32_fused<<<dim3(NBLK), dim3(256), 0, stream>>>(
            (const float*)d_in[0], (const float*)d_in[1],
            (const float*)d_in[2], (float*)d_out, flag);
    }
    fa_mfma_bf16<<<dim3(NBLK), dim3(256), 0, stream>>>(
        (const unsigned short*)d_in[0], (const unsigned short*)d_in[1],
        (const unsigned short*)d_in[2], (unsigned short*)d_out, flag);
}

// Round 4
// 368.713 us; speedup vs baseline: 14.6978x; 1.0603x over previous
//
#include <hip/hip_runtime.h>

#define Sq 2048
#define Dq 64
#define NH 64                    // B*H heads
#define KVBLK 64                 // KV rows per iteration
#define NKVIT (Sq / KVBLK)       // 32
#define PT_STRIDE 72             // P lds row stride (bf16 elems)

// ---- pre kernel geometry: 8 waves, 128 q-rows per block ----
#define QBLK_P 128
#define NQB_P (Sq / QBLK_P)      // 16
#define NBLK_P (NH * NQB_P)      // 1024 blocks (8-XCD bijective)

// ---- legacy geometry (fused fallback + bf16 path) ----
#define QBLK 64
#define NQB (Sq / QBLK)          // 32
#define NBLK (NH * NQB)          // 2048

#define TILE_ELEMS 4096          // 64x64 bf16 per tile image
#define IMG_TILES (NH * NKVIT)   // 2048 tiles per image
#define IMG_BYTES ((size_t)IMG_TILES * TILE_ELEMS * 2)   // 16,777,216 B
#define WS_IMG_OFF 4096
#define WS_NEEDED (WS_IMG_OFF + 3 * IMG_BYTES)           // ~50.3 MB

#define QK_SCALE (0.125f * 1.44269504088896f)  // 1/sqrt(D) * log2(e)
#define DEFER_THR 8.0f                          // T13: P bounded by 2^8

typedef __attribute__((ext_vector_type(8))) short bf16x8;   // 8 bf16 = 4 VGPR
typedef __attribute__((ext_vector_type(4))) float f32x4;    // MFMA acc

// ---------- bf16 helpers ----------
__device__ __forceinline__ float bflo(unsigned int u) {
    union { unsigned int i; float f; } x; x.i = u << 16; return x.f;
}
__device__ __forceinline__ unsigned int f2bf(float f) {
    union { float f; unsigned int i; } x; x.f = f;
    return (x.i + 0x7fffu + ((x.i >> 16) & 1u)) >> 16;   // RNE
}

// ---------- dtype detector (deterministic; measured flag=0 on this data) ----------
__global__ void detect_dtype(const unsigned int* __restrict__ Q,
                             int* __restrict__ flag) {
    unsigned int u = Q[threadIdx.x];
    float a = fabsf(bflo(u));
    bool sane = (a >= 9.3e-10f) && (a <= 64.0f);
    unsigned long long b = __ballot(sane);
    if (threadIdx.x == 0) *flag = (__builtin_popcountll(b) >= 48) ? 1 : 0;
}

// ---------- async global->LDS, 16B per lane ----------
__device__ __forceinline__ void gload_lds16(const unsigned short* g, unsigned short* l) {
    __builtin_amdgcn_global_load_lds(
        (const __attribute__((address_space(1))) void*)g,
        (__attribute__((address_space(3))) void*)l, 16, 0, 0);
}

// Vt (= V^T [d][kv]) element index with XOR swizzle (write & read use the same map).
__device__ __forceinline__ int vt_swz(int d, int kv) {
    return (d * KVBLK + kv) ^ ((((d & 7) ^ ((d >> 3) & 7))) << 3);
}

// =====================================================================
// Pre-pass: K -> (Khi,Klo) bf16 split, V -> V^T bf16, tiles stored in
// workspace in the exact swizzled LDS-image order. One block per tile.
// =====================================================================
__global__ __launch_bounds__(256) void convert_kv(
    const float* __restrict__ K, const float* __restrict__ V,
    unsigned short* __restrict__ img, const int* __restrict__ flag)
{
    if (*flag) return;
    __shared__ __align__(16) unsigned short VtL[TILE_ELEMS];

    const int tile = (int)blockIdx.x;
    const int tid  = threadIdx.x;
    const size_t gbase = (size_t)tile * (KVBLK * Dq);

    unsigned short* khi = img + (size_t)tile * TILE_ELEMS;
    unsigned short* klo = img + (size_t)(IMG_TILES + tile) * TILE_ELEMS;
    unsigned short* vtg = img + (size_t)(2 * IMG_TILES + tile) * TILE_ELEMS;

    const float4* kt4 = (const float4*)(K + gbase);
    const float4* vt4 = (const float4*)(V + gbase);

    #pragma unroll
    for (int c = 0; c < 4; ++c) {
        const int r  = (c * 256 + tid) >> 4;     // row 0..63
        const int c0 = (tid & 15) * 4;           // col base
        {
            float4 u4 = kt4[c * 256 + tid];
            float xs[4] = {u4.x, u4.y, u4.z, u4.w};
            unsigned int hp[2], lp[2];
            #pragma unroll
            for (int e = 0; e < 2; ++e) {
                unsigned int u0 = __float_as_uint(xs[2*e]);
                unsigned int u1 = __float_as_uint(xs[2*e+1]);
                hp[e] = (u0 >> 16) | (u1 & 0xffff0000u);
                float h0 = __uint_as_float(u0 & 0xffff0000u);
                float h1 = __uint_as_float(u1 & 0xffff0000u);
                lp[e] = (__float_as_uint(xs[2*e] - h0) >> 16)
                      | (__float_as_uint(xs[2*e+1] - h1) & 0xffff0000u);
            }
            const int sw = c0 ^ ((r & 7) << 3);
            *(uint2*)(khi + r * 64 + sw) = make_uint2(hp[0], hp[1]);
            *(uint2*)(klo + r * 64 + sw) = make_uint2(lp[0], lp[1]);
        }
        {
            float4 u4 = vt4[c * 256 + tid];
            float xs[4] = {u4.x, u4.y, u4.z, u4.w};
            #pragma unroll
            for (int e = 0; e < 4; ++e)
                VtL[vt_swz(c0 + e, r)] = (unsigned short)f2bf(xs[e]);
        }
    }
    __syncthreads();
    #pragma unroll
    for (int c = 0; c < 2; ++c)
        *(uint4*)(vtg + (c * 256 + tid) * 8) = *(const uint4*)(VtL + (c * 256 + tid) * 8);
}

// =====================================================================
// Main fp32-input MFMA flash attention: 8 waves, 128 q-rows per block,
// lsum accumulated on the matrix pipe (mfma with ones-B).
// =====================================================================
__global__ __launch_bounds__(512, 6) void fa_mfma_f32_pre(
    const float* __restrict__ Q, const unsigned short* __restrict__ img,
    float* __restrict__ O, const int* __restrict__ flag)
{
    if (*flag) return;

    __shared__ __align__(16) unsigned short Kh[TILE_ELEMS];        // 8 KiB
    __shared__ __align__(16) unsigned short Kl[TILE_ELEMS];        // 8 KiB
    __shared__ __align__(16) unsigned short Vt[TILE_ELEMS];        // 8 KiB
    __shared__ __align__(16) unsigned short Pl[8][16 * PT_STRIDE]; // 18 KiB

    const int tid  = threadIdx.x;
    const int lane = tid & 63;
    const int w    = tid >> 6;       // wave 0..7
    const int l15  = lane & 15;
    const int lg   = lane >> 4;

    // XCD-aware bijective swizzle: 1024 blocks = 8 XCDs x 128
    const int bid  = (int)blockIdx.x;
    const int blk  = (bid & 7) * (NBLK_P / 8) + (bid >> 3);
    const int head = blk >> 4;               // 16 q-blocks per head
    const int q0   = (blk & 15) * QBLK_P;
    const size_t hb = (size_t)head * (Sq * Dq);

    // ---- Q fragments: scaled by 1/8*log2e, hi/lo bf16 split ----
    bf16x8 qh[2], ql[2];
    {
        const float4* qv = (const float4*)(Q + hb + (size_t)(q0 + w * 16 + l15) * Dq + lg * 8);
        #pragma unroll
        for (int s = 0; s < 2; ++s) {
            float xs[8];
            #pragma unroll
            for (int j4 = 0; j4 < 2; ++j4) {
                float4 u = qv[s * 8 + j4];
                xs[j4*4+0]=u.x; xs[j4*4+1]=u.y; xs[j4*4+2]=u.z; xs[j4*4+3]=u.w;
            }
            #pragma unroll
            for (int j = 0; j < 8; ++j) {
                float x = xs[j] * QK_SCALE;
                unsigned int u = __float_as_uint(x);
                float hf = __uint_as_float(u & 0xffff0000u);
                qh[s][j] = (short)(u >> 16);
                ql[s][j] = (short)(__float_as_uint(x - hf) >> 16);
            }
        }
    }

    // ones B-fragment for lsum-via-MFMA (all cols identical -> each col = row sum)
    bf16x8 onesb;
    #pragma unroll
    for (int j = 0; j < 8; ++j) onesb[j] = (short)0x3F80;   // bf16 1.0

    f32x4 oacc[4];
    #pragma unroll
    for (int dt = 0; dt < 4; ++dt) oacc[dt] = (f32x4){0.f, 0.f, 0.f, 0.f};
    f32x4 lacc = (f32x4){0.f, 0.f, 0.f, 0.f};
    float mrow[4];
    #pragma unroll
    for (int r = 0; r < 4; ++r) mrow[r] = -1e30f;

    const unsigned short* khi_h = img + (size_t)(head * NKVIT) * TILE_ELEMS;
    const unsigned short* klo_h = img + (size_t)(IMG_TILES + head * NKVIT) * TILE_ELEMS;
    const unsigned short* vtg_h = img + (size_t)(2 * IMG_TILES + head * NKVIT) * TILE_ELEMS;

    for (int it = 0; it < NKVIT; ++it) {
        __syncthreads();   // all waves done reading previous tile

        // ---- stage tile images: 512 thr x 16B = one tile per pass ----
        const size_t toff = (size_t)it * TILE_ELEMS + tid * 8;
        gload_lds16(khi_h + toff, Kh + tid * 8);
        gload_lds16(klo_h + toff, Kl + tid * 8);
        gload_lds16(vtg_h + toff, Vt + tid * 8);
        asm volatile("s_waitcnt vmcnt(0)" ::: "memory");
        __syncthreads();   // tile visible to all waves

        // ---- QK^T hi/lo split: S = Qh Kh + Qh Kl + Ql Kh (log2 units) ----
        f32x4 sacc[4];
        #pragma unroll
        for (int nt = 0; nt < 4; ++nt) sacc[nt] = (f32x4){0.f, 0.f, 0.f, 0.f};
        #pragma unroll
        for (int s = 0; s < 2; ++s) {
            #pragma unroll
            for (int nt = 0; nt < 4; ++nt) {
                const int n = nt * 16 + l15;
                const int off = n * 64 + ((s * 32 + lg * 8) ^ ((n & 7) << 3));
                bf16x8 khf = *(const bf16x8*)(Kh + off);
                bf16x8 klf = *(const bf16x8*)(Kl + off);
                sacc[nt] = __builtin_amdgcn_mfma_f32_16x16x32_bf16(qh[s], khf, sacc[nt], 0, 0, 0);
                sacc[nt] = __builtin_amdgcn_mfma_f32_16x16x32_bf16(qh[s], klf, sacc[nt], 0, 0, 0);
                sacc[nt] = __builtin_amdgcn_mfma_f32_16x16x32_bf16(ql[s], khf, sacc[nt], 0, 0, 0);
            }
        }

        // ---- online softmax, exp2 domain, defer-max (T13) ----
        float pmax[4];
        #pragma unroll
        for (int r = 0; r < 4; ++r) {
            float t = fmaxf(fmaxf(sacc[0][r], sacc[1][r]), fmaxf(sacc[2][r], sacc[3][r]));
            #pragma unroll
            for (int msk = 1; msk <= 8; msk <<= 1)
                t = fmaxf(t, __shfl_xor(t, msk, 64));
            pmax[r] = t;
        }
        bool grow = (pmax[0] > mrow[0] + DEFER_THR) | (pmax[1] > mrow[1] + DEFER_THR)
                  | (pmax[2] > mrow[2] + DEFER_THR) | (pmax[3] > mrow[3] + DEFER_THR);
        if (__any(grow)) {
            f32x4 av;
            #pragma unroll
            for (int r = 0; r < 4; ++r) {
                float mnew = fmaxf(mrow[r], pmax[r]);
                av[r] = exp2f(mrow[r] - mnew);
                mrow[r] = mnew;
            }
            #pragma unroll
            for (int dt = 0; dt < 4; ++dt) oacc[dt] *= av;
            lacc *= av;
        }
        #pragma unroll
        for (int nt = 0; nt < 4; ++nt) {
            #pragma unroll
            for (int r = 0; r < 4; ++r)
                sacc[nt][r] = exp2f(sacc[nt][r] - mrow[r]);   // bounded by 2^8
        }

        // ---- P -> per-wave LDS (RNE bf16), read back as A-fragments ----
        unsigned short* pw = &Pl[w][0];
        #pragma unroll
        for (int nt = 0; nt < 4; ++nt) {
            const int cc = nt * 16 + l15;
            #pragma unroll
            for (int r = 0; r < 4; ++r)
                pw[(lg * 4 + r) * PT_STRIDE + cc] = (unsigned short)f2bf(sacc[nt][r]);
        }

        // ---- PV + lsum: O += P*V ; l += P*1 (matrix pipe) ----
        #pragma unroll
        for (int s2 = 0; s2 < 2; ++s2) {
            bf16x8 pf = *(const bf16x8*)(pw + l15 * PT_STRIDE + s2 * 32 + lg * 8);
            lacc = __builtin_amdgcn_mfma_f32_16x16x32_bf16(pf, onesb, lacc, 0, 0, 0);
            #pragma unroll
            for (int dt = 0; dt < 4; ++dt) {
                const int d = dt * 16 + l15;
                bf16x8 vf = *(const bf16x8*)(Vt + vt_swz(d, s2 * 32 + lg * 8));
                oacc[dt] = __builtin_amdgcn_mfma_f32_16x16x32_bf16(pf, vf, oacc[dt], 0, 0, 0);
            }
        }
    }

    // ---- epilogue: divide by l (from lacc), store fp32 ----
    float inv4[4];
    #pragma unroll
    for (int r = 0; r < 4; ++r) inv4[r] = 1.f / lacc[r];
    float* ob = O + hb + (size_t)(q0 + w * 16) * Dq;
    #pragma unroll
    for (int dt = 0; dt < 4; ++dt) {
        #pragma unroll
        for (int r = 0; r < 4; ++r)
            ob[(size_t)(lg * 4 + r) * Dq + dt * 16 + l15] = oacc[dt][r] * inv4[r];
    }
}

// =====================================================================
// Fallback fused fp32 kernel (used when ws too small) — round-3 version
// =====================================================================
__global__ __launch_bounds__(256, 2) void fa_mfma_f32_fused(
    const float* __restrict__ Q, const float* __restrict__ K,
    const float* __restrict__ V, float* __restrict__ O,
    const int* __restrict__ flag)
{
    if (*flag) return;

    __shared__ __align__(16) unsigned short Kh[KVBLK * Dq];
    __shared__ __align__(16) unsigned short Kl[KVBLK * Dq];
    __shared__ __align__(16) unsigned short Vt[Dq * KVBLK];
    __shared__ __align__(16) unsigned short Pl[4][16 * PT_STRIDE];

    const int tid  = threadIdx.x;
    const int lane = tid & 63;
    const int w    = tid >> 6;
    const int l15  = lane & 15;
    const int lg   = lane >> 4;

    const int bid  = (int)blockIdx.x;
    const int blk  = (bid & 7) * (NBLK / 8) + (bid >> 3);
    const int head = blk >> 5;
    const int q0   = (blk & 31) * QBLK;
    const size_t hb = (size_t)head * (Sq * Dq);

    bf16x8 qh[2], ql[2];
    {
        const float* qp = Q + hb + (size_t)(q0 + w * 16 + l15) * Dq + lg * 8;
        #pragma unroll
        for (int s = 0; s < 2; ++s) {
            #pragma unroll
            for (int j = 0; j < 8; ++j) {
                float x = qp[s * 32 + j] * 0.125f;
                unsigned int u = __float_as_uint(x);
                float hf = __uint_as_float(u & 0xffff0000u);
                qh[s][j] = (short)(u >> 16);
                ql[s][j] = (short)(__float_as_uint(x - hf) >> 16);
            }
        }
    }

    f32x4 oacc[4];
    #pragma unroll
    for (int dt = 0; dt < 4; ++dt) oacc[dt] = (f32x4){0.f, 0.f, 0.f, 0.f};
    float mrow[4], lrow[4];
    #pragma unroll
    for (int r = 0; r < 4; ++r) { mrow[r] = -1e30f; lrow[r] = 0.f; }

    const float* kbase = K + hb;
    const float* vbase = V + hb;

    float4 kr[4], vr[4];
    {
        const float4* kt4 = (const float4*)kbase;
        const float4* vt4 = (const float4*)vbase;
        #pragma unroll
        for (int c = 0; c < 4; ++c) { kr[c] = kt4[c * 256 + tid]; vr[c] = vt4[c * 256 + tid]; }
    }

    for (int it = 0; it < NKVIT; ++it) {
        __syncthreads();
        #pragma unroll
        for (int c = 0; c < 4; ++c) {
            const int r  = c * 16 + (tid >> 4);
            const int c0 = (tid & 15) * 4;
            const int sw = c0 ^ ((r & 7) << 3);
            float xs[4] = {kr[c].x, kr[c].y, kr[c].z, kr[c].w};
            unsigned int hp[2], lp[2];
            #pragma unroll
            for (int e = 0; e < 2; ++e) {
                unsigned int u0 = __float_as_uint(xs[2*e]);
                unsigned int u1 = __float_as_uint(xs[2*e+1]);
                hp[e] = (u0 >> 16) | (u1 & 0xffff0000u);
                float h0 = __uint_as_float(u0 & 0xffff0000u);
                float h1 = __uint_as_float(u1 & 0xffff0000u);
                lp[e] = (__float_as_uint(xs[2*e] - h0) >> 16)
                      | (__float_as_uint(xs[2*e+1] - h1) & 0xffff0000u);
            }
            *(uint2*)(Kh + r * 64 + sw) = make_uint2(hp[0], hp[1]);
            *(uint2*)(Kl + r * 64 + sw) = make_uint2(lp[0], lp[1]);
        }
        #pragma unroll
        for (int c = 0; c < 4; ++c) {
            const int kv = c * 16 + (tid >> 4);
            const int d0 = (tid & 15) * 4;
            float xs[4] = {vr[c].x, vr[c].y, vr[c].z, vr[c].w};
            #pragma unroll
            for (int e = 0; e < 4; ++e)
                Vt[vt_swz(d0 + e, kv)] = (unsigned short)f2bf(xs[e]);
        }
        __syncthreads();

        if (it + 1 < NKVIT) {
            const float4* kt4 = (const float4*)(kbase + (size_t)(it + 1) * KVBLK * Dq);
            const float4* vt4 = (const float4*)(vbase + (size_t)(it + 1) * KVBLK * Dq);
            #pragma unroll
            for (int c = 0; c < 4; ++c) { kr[c] = kt4[c * 256 + tid]; vr[c] = vt4[c * 256 + tid]; }
        }

        f32x4 sacc[4];
        #pragma unroll
        for (int nt = 0; nt < 4; ++nt) sacc[nt] = (f32x4){0.f, 0.f, 0.f, 0.f};
        #pragma unroll
        for (int s = 0; s < 2; ++s) {
            #pragma unroll
            for (int nt = 0; nt < 4; ++nt) {
                const int n = nt * 16 + l15;
                const int off = n * 64 + ((s * 32 + lg * 8) ^ ((n & 7) << 3));
                bf16x8 khf = *(const bf16x8*)(Kh + off);
                bf16x8 klf = *(const bf16x8*)(Kl + off);
                sacc[nt] = __builtin_amdgcn_mfma_f32_16x16x32_bf16(qh[s], khf, sacc[nt], 0, 0, 0);
                sacc[nt] = __builtin_amdgcn_mfma_f32_16x16x32_bf16(qh[s], klf, sacc[nt], 0, 0, 0);
                sacc[nt] = __builtin_amdgcn_mfma_f32_16x16x32_bf16(ql[s], khf, sacc[nt], 0, 0, 0);
            }
        }

        float mnew[4], alpha[4];
        #pragma unroll
        for (int r = 0; r < 4; ++r) {
            float t = fmaxf(fmaxf(sacc[0][r], sacc[1][r]), fmaxf(sacc[2][r], sacc[3][r]));
            #pragma unroll
            for (int msk = 1; msk <= 8; msk <<= 1)
                t = fmaxf(t, __shfl_xor(t, msk, 64));
            mnew[r]  = fmaxf(mrow[r], t);
            alpha[r] = __expf(mrow[r] - mnew[r]);
            mrow[r]  = mnew[r];
        }
        float psum[4] = {0.f, 0.f, 0.f, 0.f};
        #pragma unroll
        for (int nt = 0; nt < 4; ++nt) {
            #pragma unroll
            for (int r = 0; r < 4; ++r) {
                float p = __expf(sacc[nt][r] - mnew[r]);
                sacc[nt][r] = p;
                psum[r] += p;
            }
        }
        #pragma unroll
        for (int r = 0; r < 4; ++r) {
            float t = psum[r];
            #pragma unroll
            for (int msk = 1; msk <= 8; msk <<= 1)
                t += __shfl_xor(t, msk, 64);
            lrow[r] = lrow[r] * alpha[r] + t;
        }
        {
            f32x4 av; av[0] = alpha[0]; av[1] = alpha[1]; av[2] = alpha[2]; av[3] = alpha[3];
            #pragma unroll
            for (int dt = 0; dt < 4; ++dt) oacc[dt] *= av;
        }

        unsigned short* pw = &Pl[w][0];
        #pragma unroll
        for (int nt = 0; nt < 4; ++nt) {
            const int cc = nt * 16 + l15;
            #pragma unroll
            for (int r = 0; r < 4; ++r)
                pw[(lg * 4 + r) * PT_STRIDE + cc] = (unsigned short)f2bf(sacc[nt][r]);
        }

        #pragma unroll
        for (int s2 = 0; s2 < 2; ++s2) {
            bf16x8 pf = *(const bf16x8*)(pw + l15 * PT_STRIDE + s2 * 32 + lg * 8);
            #pragma unroll
            for (int dt = 0; dt < 4; ++dt) {
                const int d = dt * 16 + l15;
                bf16x8 vf = *(const bf16x8*)(Vt + vt_swz(d, s2 * 32 + lg * 8));
                oacc[dt] = __builtin_amdgcn_mfma_f32_16x16x32_bf16(pf, vf, oacc[dt], 0, 0, 0);
            }
        }
    }

    float inv4[4];
    #pragma unroll
    for (int r = 0; r < 4; ++r) inv4[r] = 1.f / lrow[r];
    float* ob = O + hb + (size_t)(q0 + w * 16) * Dq;
    #pragma unroll
    for (int dt = 0; dt < 4; ++dt) {
        #pragma unroll
        for (int r = 0; r < 4; ++r)
            ob[(size_t)(lg * 4 + r) * Dq + dt * 16 + l15] = oacc[dt][r] * inv4[r];
    }
}

// =====================================================================
// bf16-input MFMA flash attention (flag=1 robustness; unchanged)
// =====================================================================
__global__ __launch_bounds__(256, 3) void fa_mfma_bf16(
    const unsigned short* __restrict__ Q, const unsigned short* __restrict__ K,
    const unsigned short* __restrict__ V, unsigned short* __restrict__ O,
    const int* __restrict__ flag)
{
    if (!(*flag)) return;

    __shared__ __align__(16) unsigned short Kt[KVBLK * Dq];
    __shared__ __align__(16) unsigned short Vt[Dq * KVBLK];
    __shared__ __align__(16) unsigned short Pl[4][16 * PT_STRIDE];

    const int tid  = threadIdx.x;
    const int lane = tid & 63;
    const int w    = tid >> 6;
    const int l15  = lane & 15;
    const int lg   = lane >> 4;

    const int bid  = (int)blockIdx.x;
    const int blk  = (bid & 7) * (NBLK / 8) + (bid >> 3);
    const int head = blk >> 5;
    const int q0   = (blk & 31) * QBLK;
    const size_t hb = (size_t)head * (Sq * Dq);

    bf16x8 qf[2];
    {
        const bf16x8* qp = (const bf16x8*)(Q + hb + (size_t)(q0 + w * 16 + l15) * Dq);
        qf[0] = qp[lg];
        qf[1] = qp[4 + lg];
    }

    f32x4 oacc[4];
    #pragma unroll
    for (int dt = 0; dt < 4; ++dt) oacc[dt] = (f32x4){0.f, 0.f, 0.f, 0.f};
    float mrow[4], lrow[4];
    #pragma unroll
    for (int r = 0; r < 4; ++r) { mrow[r] = -1e30f; lrow[r] = 0.f; }

    const int sr = tid >> 3;
    const int sc = tid & 7;
    const int kswz_elem = (sc * 8) ^ ((sr & 7) << 3);

    for (int it = 0; it < NKVIT; ++it) {
        const int kv0 = it * KVBLK;
        __syncthreads();
        #pragma unroll
        for (int c = 0; c < 2; ++c) {
            gload_lds16(K + hb + (size_t)(kv0 + c * 32 + sr) * Dq + kswz_elem,
                        Kt + c * 2048 + tid * 8);
        }
        uint4 vreg[2];
        #pragma unroll
        for (int c = 0; c < 2; ++c)
            vreg[c] = *(const uint4*)(V + hb + (size_t)(kv0 + c * 32 + sr) * Dq + sc * 8);

        asm volatile("s_waitcnt vmcnt(0)" ::: "memory");

        #pragma unroll
        for (int c = 0; c < 2; ++c) {
            const int kv = c * 32 + sr;
            unsigned int vu[4] = { vreg[c].x, vreg[c].y, vreg[c].z, vreg[c].w };
            #pragma unroll
            for (int e2 = 0; e2 < 4; ++e2) {
                const int d0 = sc * 8 + e2 * 2;
                Vt[vt_swz(d0,     kv)] = (unsigned short)(vu[e2] & 0xffffu);
                Vt[vt_swz(d0 + 1, kv)] = (unsigned short)(vu[e2] >> 16);
            }
        }
        __syncthreads();

        f32x4 sacc[4];
        #pragma unroll
        for (int nt = 0; nt < 4; ++nt) sacc[nt] = (f32x4){0.f, 0.f, 0.f, 0.f};
        #pragma unroll
        for (int s = 0; s < 2; ++s) {
            #pragma unroll
            for (int nt = 0; nt < 4; ++nt) {
                const int n = nt * 16 + l15;
                bf16x8 kf = *(const bf16x8*)(Kt + n * 64 + ((s * 32 + lg * 8) ^ ((n & 7) << 3)));
                sacc[nt] = __builtin_amdgcn_mfma_f32_16x16x32_bf16(qf[s], kf, sacc[nt], 0, 0, 0);
            }
        }
        #pragma unroll
        for (int nt = 0; nt < 4; ++nt) sacc[nt] *= 0.125f;

        float mnew[4], alpha[4];
        #pragma unroll
        for (int r = 0; r < 4; ++r) {
            float t = fmaxf(fmaxf(sacc[0][r], sacc[1][r]), fmaxf(sacc[2][r], sacc[3][r]));
            #pragma unroll
            for (int msk = 1; msk <= 8; msk <<= 1)
                t = fmaxf(t, __shfl_xor(t, msk, 64));
            mnew[r]  = fmaxf(mrow[r], t);
            alpha[r] = __expf(mrow[r] - mnew[r]);
            mrow[r]  = mnew[r];
        }
        float psum[4] = {0.f, 0.f, 0.f, 0.f};
        #pragma unroll
        for (int nt = 0; nt < 4; ++nt) {
            #pragma unroll
            for (int r = 0; r < 4; ++r) {
                float p = __expf(sacc[nt][r] - mnew[r]);
                sacc[nt][r] = p;
                psum[r] += p;
            }
        }
        #pragma unroll
        for (int r = 0; r < 4; ++r) {
            float t = psum[r];
            #pragma unroll
            for (int msk = 1; msk <= 8; msk <<= 1)
                t += __shfl_xor(t, msk, 64);
            lrow[r] = lrow[r] * alpha[r] + t;
        }
        {
            f32x4 av; av[0] = alpha[0]; av[1] = alpha[1]; av[2] = alpha[2]; av[3] = alpha[3];
            #pragma unroll
            for (int dt = 0; dt < 4; ++dt) oacc[dt] *= av;
        }

        unsigned short* pw = &Pl[w][0];
        #pragma unroll
        for (int nt = 0; nt < 4; ++nt) {
            const int cc = nt * 16 + l15;
            #pragma unroll
            for (int r = 0; r < 4; ++r)
                pw[(lg * 4 + r) * PT_STRIDE + cc] = (unsigned short)f2bf(sacc[nt][r]);
        }

        #pragma unroll
        for (int s2 = 0; s2 < 2; ++s2) {
            bf16x8 pf = *(const bf16x8*)(pw + l15 * PT_STRIDE + s2 * 32 + lg * 8);
            #pragma unroll
            for (int dt = 0; dt < 4; ++dt) {
                const int d = dt * 16 + l15;
                bf16x8 vf = *(const bf16x8*)(Vt + vt_swz(d, s2 * 32 + lg * 8));
                oacc[dt] = __builtin_amdgcn_mfma_f32_16x16x32_bf16(pf, vf, oacc[dt], 0, 0, 0);
            }
        }
    }

    float inv4[4];
    #pragma unroll
    for (int r = 0; r < 4; ++r) inv4[r] = 1.f / lrow[r];
    unsigned short* ob = O + (size_t)(head * Sq + q0 + w * 16) * Dq;
    #pragma unroll
    for (int dt = 0; dt < 4; ++dt) {
        #pragma unroll
        for (int r = 0; r < 4; ++r)
            ob[(size_t)(lg * 4 + r) * Dq + dt * 16 + l15] = (unsigned short)f2bf(oacc[dt][r] * inv4[r]);
    }
}

extern "C" void kernel_launch(void* const* d_in, const int* in_sizes, int n_in,
                              void* d_out, int out_size, void* d_ws, size_t ws_size,
                              hipStream_t stream) {
    int* flag = (int*)d_ws;
    detect_dtype<<<dim3(1), dim3(64), 0, stream>>>((const unsigned int*)d_in[0], flag);
    if (ws_size >= WS_NEEDED) {
        unsigned short* img = (unsigned short*)((char*)d_ws + WS_IMG_OFF);
        convert_kv<<<dim3(IMG_TILES), dim3(256), 0, stream>>>(
            (const float*)d_in[1], (const float*)d_in[2], img, flag);
        fa_mfma_f32_pre<<<dim3(NBLK_P), dim3(512), 0, stream>>>(
            (const float*)d_in[0], img, (float*)d_out, flag);
    } else {
        fa_mfma_f32_fused<<<dim3(NBLK), dim3(256), 0, stream>>>(
            (const float*)d_in[0], (const float*)d_in[1],
            (const float*)d_in[2], (float*)d_out, flag);
    }
    fa_mfma_bf16<<<dim3(NBLK), dim3(256), 0, stream>>>(
        (const unsigned short*)d_in[0], (const unsigned short*)d_in[1],
        (const unsigned short*)d_in[2], (unsigned short*)d_out, flag);
}

// Round 5
// 307.412 us; speedup vs baseline: 17.6288x; 1.1994x over previous
//
#include <hip/hip_runtime.h>

#define Sq 2048
#define Dq 64
#define NH 64                    // B*H heads
#define KVBLK 64                 // KV rows per iteration
#define NKVIT (Sq / KVBLK)       // 32
#define PT_STRIDE 72             // P lds row stride (bf16 elems)

// ---- pre kernel geometry: 4 waves x 32 q-rows = 128 q-rows per block ----
#define QBLK_P 128
#define NQB_P (Sq / QBLK_P)      // 16
#define NBLK_P (NH * NQB_P)      // 1024 blocks (8-XCD bijective)

// ---- legacy geometry (fused fallback + bf16 path) ----
#define QBLK 64
#define NQB (Sq / QBLK)          // 32
#define NBLK (NH * NQB)          // 2048

#define TILE_ELEMS 4096          // 64x64 bf16 per tile image
#define IMG_TILES (NH * NKVIT)   // 2048 tiles per image
#define IMG_BYTES ((size_t)IMG_TILES * TILE_ELEMS * 2)   // 16,777,216 B
#define WS_IMG_OFF 4096
#define WS_NEEDED (WS_IMG_OFF + 3 * IMG_BYTES)           // ~50.3 MB

#define QK_SCALE (0.125f * 1.44269504088896f)  // 1/sqrt(D) * log2(e)
#define DEFER_THR 8.0f                          // T13: P bounded by 2^8

typedef __attribute__((ext_vector_type(8))) short bf16x8;   // 8 bf16 = 4 VGPR
typedef __attribute__((ext_vector_type(4))) float f32x4;    // MFMA acc

// ---------- bf16 helpers ----------
__device__ __forceinline__ float bflo(unsigned int u) {
    union { unsigned int i; float f; } x; x.i = u << 16; return x.f;
}
__device__ __forceinline__ unsigned int f2bf(float f) {
    union { float f; unsigned int i; } x; x.f = f;
    return (x.i + 0x7fffu + ((x.i >> 16) & 1u)) >> 16;   // RNE
}

// ---------- dtype detector (deterministic; measured flag=0 on this data) ----------
__global__ void detect_dtype(const unsigned int* __restrict__ Q,
                             int* __restrict__ flag) {
    unsigned int u = Q[threadIdx.x];
    float a = fabsf(bflo(u));
    bool sane = (a >= 9.3e-10f) && (a <= 64.0f);
    unsigned long long b = __ballot(sane);
    if (threadIdx.x == 0) *flag = (__builtin_popcountll(b) >= 48) ? 1 : 0;
}

// ---------- async global->LDS, 16B per lane ----------
__device__ __forceinline__ void gload_lds16(const unsigned short* g, unsigned short* l) {
    __builtin_amdgcn_global_load_lds(
        (const __attribute__((address_space(1))) void*)g,
        (__attribute__((address_space(3))) void*)l, 16, 0, 0);
}

// Vt (= V^T [d][kv]) element index with XOR swizzle (write & read use the same map).
__device__ __forceinline__ int vt_swz(int d, int kv) {
    return (d * KVBLK + kv) ^ ((((d & 7) ^ ((d >> 3) & 7))) << 3);
}

// =====================================================================
// Pre-pass: K -> (Khi,Klo) bf16 split, V -> V^T bf16, tiles stored in
// workspace in the exact swizzled LDS-image order. One block per tile.
// =====================================================================
__global__ __launch_bounds__(256) void convert_kv(
    const float* __restrict__ K, const float* __restrict__ V,
    unsigned short* __restrict__ img, const int* __restrict__ flag)
{
    if (*flag) return;
    __shared__ __align__(16) unsigned short VtL[TILE_ELEMS];

    const int tile = (int)blockIdx.x;
    const int tid  = threadIdx.x;
    const size_t gbase = (size_t)tile * (KVBLK * Dq);

    unsigned short* khi = img + (size_t)tile * TILE_ELEMS;
    unsigned short* klo = img + (size_t)(IMG_TILES + tile) * TILE_ELEMS;
    unsigned short* vtg = img + (size_t)(2 * IMG_TILES + tile) * TILE_ELEMS;

    const float4* kt4 = (const float4*)(K + gbase);
    const float4* vt4 = (const float4*)(V + gbase);

    #pragma unroll
    for (int c = 0; c < 4; ++c) {
        const int r  = (c * 256 + tid) >> 4;     // row 0..63
        const int c0 = (tid & 15) * 4;           // col base
        {
            float4 u4 = kt4[c * 256 + tid];
            float xs[4] = {u4.x, u4.y, u4.z, u4.w};
            unsigned int hp[2], lp[2];
            #pragma unroll
            for (int e = 0; e < 2; ++e) {
                unsigned int u0 = __float_as_uint(xs[2*e]);
                unsigned int u1 = __float_as_uint(xs[2*e+1]);
                hp[e] = (u0 >> 16) | (u1 & 0xffff0000u);
                float h0 = __uint_as_float(u0 & 0xffff0000u);
                float h1 = __uint_as_float(u1 & 0xffff0000u);
                lp[e] = (__float_as_uint(xs[2*e] - h0) >> 16)
                      | (__float_as_uint(xs[2*e+1] - h1) & 0xffff0000u);
            }
            const int sw = c0 ^ ((r & 7) << 3);
            *(uint2*)(khi + r * 64 + sw) = make_uint2(hp[0], hp[1]);
            *(uint2*)(klo + r * 64 + sw) = make_uint2(lp[0], lp[1]);
        }
        {
            float4 u4 = vt4[c * 256 + tid];
            float xs[4] = {u4.x, u4.y, u4.z, u4.w};
            #pragma unroll
            for (int e = 0; e < 4; ++e)
                VtL[vt_swz(c0 + e, r)] = (unsigned short)f2bf(xs[e]);
        }
    }
    __syncthreads();
    #pragma unroll
    for (int c = 0; c < 2; ++c)
        *(uint4*)(vtg + (c * 256 + tid) * 8) = *(const uint4*)(VtL + (c * 256 + tid) * 8);
}

// ---- softmax common-path (shfl-free defer-max; full reduce only on grow) ----
#define SOFTMAX_BODY(SACC, MR, OA, LA)                                          \
{                                                                               \
    float rmax[4];                                                              \
    _Pragma("unroll")                                                           \
    for (int r = 0; r < 4; ++r)                                                 \
        rmax[r] = fmaxf(fmaxf(SACC[0][r], SACC[1][r]),                          \
                        fmaxf(SACC[2][r], SACC[3][r]));                         \
    bool grow = (rmax[0] > MR[0] + DEFER_THR) | (rmax[1] > MR[1] + DEFER_THR)   \
              | (rmax[2] > MR[2] + DEFER_THR) | (rmax[3] > MR[3] + DEFER_THR);  \
    if (__any(grow)) {                                                          \
        f32x4 av;                                                               \
        _Pragma("unroll")                                                       \
        for (int r = 0; r < 4; ++r) {                                           \
            float t = rmax[r];                                                  \
            _Pragma("unroll")                                                   \
            for (int msk = 1; msk <= 8; msk <<= 1)                              \
                t = fmaxf(t, __shfl_xor(t, msk, 64));                           \
            float mnew = fmaxf(MR[r], t);                                       \
            av[r] = exp2f(MR[r] - mnew);                                        \
            MR[r] = mnew;                                                       \
        }                                                                       \
        _Pragma("unroll")                                                       \
        for (int dt = 0; dt < 4; ++dt) OA[dt] *= av;                            \
        LA *= av;                                                               \
    }                                                                           \
    _Pragma("unroll")                                                           \
    for (int nt = 0; nt < 4; ++nt) {                                            \
        _Pragma("unroll")                                                       \
        for (int r = 0; r < 4; ++r)                                             \
            SACC[nt][r] = exp2f(SACC[nt][r] - MR[r]);                           \
    }                                                                           \
}

// =====================================================================
// Main fp32-input MFMA flash attention: 4 waves x 32 q-rows (2 subtiles
// sharing every K/V B-fragment read), shfl-free defer-max softmax,
// lsum on the matrix pipe.
// =====================================================================
__global__ __launch_bounds__(256, 3) void fa_mfma_f32_pre(
    const float* __restrict__ Q, const unsigned short* __restrict__ img,
    float* __restrict__ O, const int* __restrict__ flag)
{
    if (*flag) return;

    __shared__ __align__(16) unsigned short Kh[TILE_ELEMS];        // 8 KiB
    __shared__ __align__(16) unsigned short Kl[TILE_ELEMS];        // 8 KiB
    __shared__ __align__(16) unsigned short Vt[TILE_ELEMS];        // 8 KiB
    __shared__ __align__(16) unsigned short Pl[4][16 * PT_STRIDE]; // 9 KiB

    const int tid  = threadIdx.x;
    const int lane = tid & 63;
    const int w    = tid >> 6;       // wave 0..3
    const int l15  = lane & 15;
    const int lg   = lane >> 4;

    // XCD-aware bijective swizzle: 1024 blocks = 8 XCDs x 128
    const int bid  = (int)blockIdx.x;
    const int blk  = (bid & 7) * (NBLK_P / 8) + (bid >> 3);
    const int head = blk >> 4;               // 16 q-blocks per head
    const int q0   = (blk & 15) * QBLK_P;
    const size_t hb = (size_t)head * (Sq * Dq);

    // ---- Q fragments: 2 subtiles (m), scaled by 1/8*log2e, hi/lo split ----
    bf16x8 qh[2][2], ql[2][2];   // [m][s]
    #pragma unroll
    for (int m = 0; m < 2; ++m) {
        const float4* qv = (const float4*)(Q + hb
            + (size_t)(q0 + w * 32 + m * 16 + l15) * Dq + lg * 8);
        #pragma unroll
        for (int s = 0; s < 2; ++s) {
            float xs[8];
            #pragma unroll
            for (int j4 = 0; j4 < 2; ++j4) {
                float4 u = qv[s * 8 + j4];
                xs[j4*4+0]=u.x; xs[j4*4+1]=u.y; xs[j4*4+2]=u.z; xs[j4*4+3]=u.w;
            }
            #pragma unroll
            for (int j = 0; j < 8; ++j) {
                float x = xs[j] * QK_SCALE;
                unsigned int u = __float_as_uint(x);
                float hf = __uint_as_float(u & 0xffff0000u);
                qh[m][s][j] = (short)(u >> 16);
                ql[m][s][j] = (short)(__float_as_uint(x - hf) >> 16);
            }
        }
    }

    bf16x8 onesb;
    #pragma unroll
    for (int j = 0; j < 8; ++j) onesb[j] = (short)0x3F80;   // bf16 1.0

    f32x4 oacc0[4], oacc1[4];
    #pragma unroll
    for (int dt = 0; dt < 4; ++dt) {
        oacc0[dt] = (f32x4){0.f, 0.f, 0.f, 0.f};
        oacc1[dt] = (f32x4){0.f, 0.f, 0.f, 0.f};
    }
    f32x4 lacc0 = (f32x4){0.f,0.f,0.f,0.f}, lacc1 = (f32x4){0.f,0.f,0.f,0.f};
    float mrow0[4], mrow1[4];
    #pragma unroll
    for (int r = 0; r < 4; ++r) { mrow0[r] = -1e30f; mrow1[r] = -1e30f; }

    const unsigned short* khi_h = img + (size_t)(head * NKVIT) * TILE_ELEMS;
    const unsigned short* klo_h = img + (size_t)(IMG_TILES + head * NKVIT) * TILE_ELEMS;
    const unsigned short* vtg_h = img + (size_t)(2 * IMG_TILES + head * NKVIT) * TILE_ELEMS;

    for (int it = 0; it < NKVIT; ++it) {
        __syncthreads();   // all waves done reading previous tile

        // ---- stage tile images: 256 thr x 16B x 2 passes per buffer ----
        const size_t toff = (size_t)it * TILE_ELEMS;
        #pragma unroll
        for (int c = 0; c < 2; ++c) {
            const int e8 = (c * 256 + tid) * 8;
            gload_lds16(khi_h + toff + e8, Kh + e8);
            gload_lds16(klo_h + toff + e8, Kl + e8);
            gload_lds16(vtg_h + toff + e8, Vt + e8);
        }
        asm volatile("s_waitcnt vmcnt(0)" ::: "memory");
        __syncthreads();   // tile visible to all waves

        // ---- QK^T for BOTH subtiles, sharing every Kh/Kl fragment read ----
        f32x4 s0[4], s1[4];
        #pragma unroll
        for (int nt = 0; nt < 4; ++nt) {
            s0[nt] = (f32x4){0.f,0.f,0.f,0.f};
            s1[nt] = (f32x4){0.f,0.f,0.f,0.f};
        }
        #pragma unroll
        for (int s = 0; s < 2; ++s) {
            #pragma unroll
            for (int nt = 0; nt < 4; ++nt) {
                const int n = nt * 16 + l15;
                const int off = n * 64 + ((s * 32 + lg * 8) ^ ((n & 7) << 3));
                bf16x8 khf = *(const bf16x8*)(Kh + off);
                bf16x8 klf = *(const bf16x8*)(Kl + off);
                s0[nt] = __builtin_amdgcn_mfma_f32_16x16x32_bf16(qh[0][s], khf, s0[nt], 0, 0, 0);
                s0[nt] = __builtin_amdgcn_mfma_f32_16x16x32_bf16(qh[0][s], klf, s0[nt], 0, 0, 0);
                s0[nt] = __builtin_amdgcn_mfma_f32_16x16x32_bf16(ql[0][s], khf, s0[nt], 0, 0, 0);
                s1[nt] = __builtin_amdgcn_mfma_f32_16x16x32_bf16(qh[1][s], khf, s1[nt], 0, 0, 0);
                s1[nt] = __builtin_amdgcn_mfma_f32_16x16x32_bf16(qh[1][s], klf, s1[nt], 0, 0, 0);
                s1[nt] = __builtin_amdgcn_mfma_f32_16x16x32_bf16(ql[1][s], khf, s1[nt], 0, 0, 0);
            }
        }

        // ---- softmax (shfl-free common path) ----
        SOFTMAX_BODY(s0, mrow0, oacc0, lacc0)
        SOFTMAX_BODY(s1, mrow1, oacc1, lacc1)

        // ---- P -> per-wave LDS (subtile-sequential), read as A-frags ----
        unsigned short* pw = &Pl[w][0];
        bf16x8 pf0[2], pf1[2];
        #pragma unroll
        for (int nt = 0; nt < 4; ++nt) {
            const int cc = nt * 16 + l15;
            #pragma unroll
            for (int r = 0; r < 4; ++r)
                pw[(lg * 4 + r) * PT_STRIDE + cc] = (unsigned short)f2bf(s0[nt][r]);
        }
        #pragma unroll
        for (int s2 = 0; s2 < 2; ++s2)
            pf0[s2] = *(const bf16x8*)(pw + l15 * PT_STRIDE + s2 * 32 + lg * 8);
        #pragma unroll
        for (int nt = 0; nt < 4; ++nt) {
            const int cc = nt * 16 + l15;
            #pragma unroll
            for (int r = 0; r < 4; ++r)
                pw[(lg * 4 + r) * PT_STRIDE + cc] = (unsigned short)f2bf(s1[nt][r]);
        }
        #pragma unroll
        for (int s2 = 0; s2 < 2; ++s2)
            pf1[s2] = *(const bf16x8*)(pw + l15 * PT_STRIDE + s2 * 32 + lg * 8);

        // ---- PV + lsum: every V fragment read serves both subtiles ----
        #pragma unroll
        for (int s2 = 0; s2 < 2; ++s2) {
            lacc0 = __builtin_amdgcn_mfma_f32_16x16x32_bf16(pf0[s2], onesb, lacc0, 0, 0, 0);
            lacc1 = __builtin_amdgcn_mfma_f32_16x16x32_bf16(pf1[s2], onesb, lacc1, 0, 0, 0);
            #pragma unroll
            for (int dt = 0; dt < 4; ++dt) {
                const int d = dt * 16 + l15;
                bf16x8 vf = *(const bf16x8*)(Vt + vt_swz(d, s2 * 32 + lg * 8));
                oacc0[dt] = __builtin_amdgcn_mfma_f32_16x16x32_bf16(pf0[s2], vf, oacc0[dt], 0, 0, 0);
                oacc1[dt] = __builtin_amdgcn_mfma_f32_16x16x32_bf16(pf1[s2], vf, oacc1[dt], 0, 0, 0);
            }
        }
    }

    // ---- epilogue ----
    {
        float inv[4];
        #pragma unroll
        for (int r = 0; r < 4; ++r) inv[r] = 1.f / lacc0[r];
        float* ob = O + hb + (size_t)(q0 + w * 32) * Dq;
        #pragma unroll
        for (int dt = 0; dt < 4; ++dt) {
            #pragma unroll
            for (int r = 0; r < 4; ++r)
                ob[(size_t)(lg * 4 + r) * Dq + dt * 16 + l15] = oacc0[dt][r] * inv[r];
        }
    }
    {
        float inv[4];
        #pragma unroll
        for (int r = 0; r < 4; ++r) inv[r] = 1.f / lacc1[r];
        float* ob = O + hb + (size_t)(q0 + w * 32 + 16) * Dq;
        #pragma unroll
        for (int dt = 0; dt < 4; ++dt) {
            #pragma unroll
            for (int r = 0; r < 4; ++r)
                ob[(size_t)(lg * 4 + r) * Dq + dt * 16 + l15] = oacc1[dt][r] * inv[r];
        }
    }
}

// =====================================================================
// Fallback fused fp32 kernel (used when ws too small) — round-3 version
// =====================================================================
__global__ __launch_bounds__(256, 2) void fa_mfma_f32_fused(
    const float* __restrict__ Q, const float* __restrict__ K,
    const float* __restrict__ V, float* __restrict__ O,
    const int* __restrict__ flag)
{
    if (*flag) return;

    __shared__ __align__(16) unsigned short Kh[KVBLK * Dq];
    __shared__ __align__(16) unsigned short Kl[KVBLK * Dq];
    __shared__ __align__(16) unsigned short Vt[Dq * KVBLK];
    __shared__ __align__(16) unsigned short Pl[4][16 * PT_STRIDE];

    const int tid  = threadIdx.x;
    const int lane = tid & 63;
    const int w    = tid >> 6;
    const int l15  = lane & 15;
    const int lg   = lane >> 4;

    const int bid  = (int)blockIdx.x;
    const int blk  = (bid & 7) * (NBLK / 8) + (bid >> 3);
    const int head = blk >> 5;
    const int q0   = (blk & 31) * QBLK;
    const size_t hb = (size_t)head * (Sq * Dq);

    bf16x8 qh[2], ql[2];
    {
        const float* qp = Q + hb + (size_t)(q0 + w * 16 + l15) * Dq + lg * 8;
        #pragma unroll
        for (int s = 0; s < 2; ++s) {
            #pragma unroll
            for (int j = 0; j < 8; ++j) {
                float x = qp[s * 32 + j] * 0.125f;
                unsigned int u = __float_as_uint(x);
                float hf = __uint_as_float(u & 0xffff0000u);
                qh[s][j] = (short)(u >> 16);
                ql[s][j] = (short)(__float_as_uint(x - hf) >> 16);
            }
        }
    }

    f32x4 oacc[4];
    #pragma unroll
    for (int dt = 0; dt < 4; ++dt) oacc[dt] = (f32x4){0.f, 0.f, 0.f, 0.f};
    float mrow[4], lrow[4];
    #pragma unroll
    for (int r = 0; r < 4; ++r) { mrow[r] = -1e30f; lrow[r] = 0.f; }

    const float* kbase = K + hb;
    const float* vbase = V + hb;

    float4 kr[4], vr[4];
    {
        const float4* kt4 = (const float4*)kbase;
        const float4* vt4 = (const float4*)vbase;
        #pragma unroll
        for (int c = 0; c < 4; ++c) { kr[c] = kt4[c * 256 + tid]; vr[c] = vt4[c * 256 + tid]; }
    }

    for (int it = 0; it < NKVIT; ++it) {
        __syncthreads();
        #pragma unroll
        for (int c = 0; c < 4; ++c) {
            const int r  = c * 16 + (tid >> 4);
            const int c0 = (tid & 15) * 4;
            const int sw = c0 ^ ((r & 7) << 3);
            float xs[4] = {kr[c].x, kr[c].y, kr[c].z, kr[c].w};
            unsigned int hp[2], lp[2];
            #pragma unroll
            for (int e = 0; e < 2; ++e) {
                unsigned int u0 = __float_as_uint(xs[2*e]);
                unsigned int u1 = __float_as_uint(xs[2*e+1]);
                hp[e] = (u0 >> 16) | (u1 & 0xffff0000u);
                float h0 = __uint_as_float(u0 & 0xffff0000u);
                float h1 = __uint_as_float(u1 & 0xffff0000u);
                lp[e] = (__float_as_uint(xs[2*e] - h0) >> 16)
                      | (__float_as_uint(xs[2*e+1] - h1) & 0xffff0000u);
            }
            *(uint2*)(Kh + r * 64 + sw) = make_uint2(hp[0], hp[1]);
            *(uint2*)(Kl + r * 64 + sw) = make_uint2(lp[0], lp[1]);
        }
        #pragma unroll
        for (int c = 0; c < 4; ++c) {
            const int kv = c * 16 + (tid >> 4);
            const int d0 = (tid & 15) * 4;
            float xs[4] = {vr[c].x, vr[c].y, vr[c].z, vr[c].w};
            #pragma unroll
            for (int e = 0; e < 4; ++e)
                Vt[vt_swz(d0 + e, kv)] = (unsigned short)f2bf(xs[e]);
        }
        __syncthreads();

        if (it + 1 < NKVIT) {
            const float4* kt4 = (const float4*)(kbase + (size_t)(it + 1) * KVBLK * Dq);
            const float4* vt4 = (const float4*)(vbase + (size_t)(it + 1) * KVBLK * Dq);
            #pragma unroll
            for (int c = 0; c < 4; ++c) { kr[c] = kt4[c * 256 + tid]; vr[c] = vt4[c * 256 + tid]; }
        }

        f32x4 sacc[4];
        #pragma unroll
        for (int nt = 0; nt < 4; ++nt) sacc[nt] = (f32x4){0.f, 0.f, 0.f, 0.f};
        #pragma unroll
        for (int s = 0; s < 2; ++s) {
            #pragma unroll
            for (int nt = 0; nt < 4; ++nt) {
                const int n = nt * 16 + l15;
                const int off = n * 64 + ((s * 32 + lg * 8) ^ ((n & 7) << 3));
                bf16x8 khf = *(const bf16x8*)(Kh + off);
                bf16x8 klf = *(const bf16x8*)(Kl + off);
                sacc[nt] = __builtin_amdgcn_mfma_f32_16x16x32_bf16(qh[s], khf, sacc[nt], 0, 0, 0);
                sacc[nt] = __builtin_amdgcn_mfma_f32_16x16x32_bf16(qh[s], klf, sacc[nt], 0, 0, 0);
                sacc[nt] = __builtin_amdgcn_mfma_f32_16x16x32_bf16(ql[s], khf, sacc[nt], 0, 0, 0);
            }
        }

        float mnew[4], alpha[4];
        #pragma unroll
        for (int r = 0; r < 4; ++r) {
            float t = fmaxf(fmaxf(sacc[0][r], sacc[1][r]), fmaxf(sacc[2][r], sacc[3][r]));
            #pragma unroll
            for (int msk = 1; msk <= 8; msk <<= 1)
                t = fmaxf(t, __shfl_xor(t, msk, 64));
            mnew[r]  = fmaxf(mrow[r], t);
            alpha[r] = __expf(mrow[r] - mnew[r]);
            mrow[r]  = mnew[r];
        }
        float psum[4] = {0.f, 0.f, 0.f, 0.f};
        #pragma unroll
        for (int nt = 0; nt < 4; ++nt) {
            #pragma unroll
            for (int r = 0; r < 4; ++r) {
                float p = __expf(sacc[nt][r] - mnew[r]);
                sacc[nt][r] = p;
                psum[r] += p;
            }
        }
        #pragma unroll
        for (int r = 0; r < 4; ++r) {
            float t = psum[r];
            #pragma unroll
            for (int msk = 1; msk <= 8; msk <<= 1)
                t += __shfl_xor(t, msk, 64);
            lrow[r] = lrow[r] * alpha[r] + t;
        }
        {
            f32x4 av; av[0] = alpha[0]; av[1] = alpha[1]; av[2] = alpha[2]; av[3] = alpha[3];
            #pragma unroll
            for (int dt = 0; dt < 4; ++dt) oacc[dt] *= av;
        }

        unsigned short* pw = &Pl[w][0];
        #pragma unroll
        for (int nt = 0; nt < 4; ++nt) {
            const int cc = nt * 16 + l15;
            #pragma unroll
            for (int r = 0; r < 4; ++r)
                pw[(lg * 4 + r) * PT_STRIDE + cc] = (unsigned short)f2bf(sacc[nt][r]);
        }

        #pragma unroll
        for (int s2 = 0; s2 < 2; ++s2) {
            bf16x8 pf = *(const bf16x8*)(pw + l15 * PT_STRIDE + s2 * 32 + lg * 8);
            #pragma unroll
            for (int dt = 0; dt < 4; ++dt) {
                const int d = dt * 16 + l15;
                bf16x8 vf = *(const bf16x8*)(Vt + vt_swz(d, s2 * 32 + lg * 8));
                oacc[dt] = __builtin_amdgcn_mfma_f32_16x16x32_bf16(pf, vf, oacc[dt], 0, 0, 0);
            }
        }
    }

    float inv4[4];
    #pragma unroll
    for (int r = 0; r < 4; ++r) inv4[r] = 1.f / lrow[r];
    float* ob = O + hb + (size_t)(q0 + w * 16) * Dq;
    #pragma unroll
    for (int dt = 0; dt < 4; ++dt) {
        #pragma unroll
        for (int r = 0; r < 4; ++r)
            ob[(size_t)(lg * 4 + r) * Dq + dt * 16 + l15] = oacc[dt][r] * inv4[r];
    }
}

// =====================================================================
// bf16-input MFMA flash attention (flag=1 robustness; unchanged)
// =====================================================================
__global__ __launch_bounds__(256, 3) void fa_mfma_bf16(
    const unsigned short* __restrict__ Q, const unsigned short* __restrict__ K,
    const unsigned short* __restrict__ V, unsigned short* __restrict__ O,
    const int* __restrict__ flag)
{
    if (!(*flag)) return;

    __shared__ __align__(16) unsigned short Kt[KVBLK * Dq];
    __shared__ __align__(16) unsigned short Vt[Dq * KVBLK];
    __shared__ __align__(16) unsigned short Pl[4][16 * PT_STRIDE];

    const int tid  = threadIdx.x;
    const int lane = tid & 63;
    const int w    = tid >> 6;
    const int l15  = lane & 15;
    const int lg   = lane >> 4;

    const int bid  = (int)blockIdx.x;
    const int blk  = (bid & 7) * (NBLK / 8) + (bid >> 3);
    const int head = blk >> 5;
    const int q0   = (blk & 31) * QBLK;
    const size_t hb = (size_t)head * (Sq * Dq);

    bf16x8 qf[2];
    {
        const bf16x8* qp = (const bf16x8*)(Q + hb + (size_t)(q0 + w * 16 + l15) * Dq);
        qf[0] = qp[lg];
        qf[1] = qp[4 + lg];
    }

    f32x4 oacc[4];
    #pragma unroll
    for (int dt = 0; dt < 4; ++dt) oacc[dt] = (f32x4){0.f, 0.f, 0.f, 0.f};
    float mrow[4], lrow[4];
    #pragma unroll
    for (int r = 0; r < 4; ++r) { mrow[r] = -1e30f; lrow[r] = 0.f; }

    const int sr = tid >> 3;
    const int sc = tid & 7;
    const int kswz_elem = (sc * 8) ^ ((sr & 7) << 3);

    for (int it = 0; it < NKVIT; ++it) {
        const int kv0 = it * KVBLK;
        __syncthreads();
        #pragma unroll
        for (int c = 0; c < 2; ++c) {
            gload_lds16(K + hb + (size_t)(kv0 + c * 32 + sr) * Dq + kswz_elem,
                        Kt + c * 2048 + tid * 8);
        }
        uint4 vreg[2];
        #pragma unroll
        for (int c = 0; c < 2; ++c)
            vreg[c] = *(const uint4*)(V + hb + (size_t)(kv0 + c * 32 + sr) * Dq + sc * 8);

        asm volatile("s_waitcnt vmcnt(0)" ::: "memory");

        #pragma unroll
        for (int c = 0; c < 2; ++c) {
            const int kv = c * 32 + sr;
            unsigned int vu[4] = { vreg[c].x, vreg[c].y, vreg[c].z, vreg[c].w };
            #pragma unroll
            for (int e2 = 0; e2 < 4; ++e2) {
                const int d0 = sc * 8 + e2 * 2;
                Vt[vt_swz(d0,     kv)] = (unsigned short)(vu[e2] & 0xffffu);
                Vt[vt_swz(d0 + 1, kv)] = (unsigned short)(vu[e2] >> 16);
            }
        }
        __syncthreads();

        f32x4 sacc[4];
        #pragma unroll
        for (int nt = 0; nt < 4; ++nt) sacc[nt] = (f32x4){0.f, 0.f, 0.f, 0.f};
        #pragma unroll
        for (int s = 0; s < 2; ++s) {
            #pragma unroll
            for (int nt = 0; nt < 4; ++nt) {
                const int n = nt * 16 + l15;
                bf16x8 kf = *(const bf16x8*)(Kt + n * 64 + ((s * 32 + lg * 8) ^ ((n & 7) << 3)));
                sacc[nt] = __builtin_amdgcn_mfma_f32_16x16x32_bf16(qf[s], kf, sacc[nt], 0, 0, 0);
            }
        }
        #pragma unroll
        for (int nt = 0; nt < 4; ++nt) sacc[nt] *= 0.125f;

        float mnew[4], alpha[4];
        #pragma unroll
        for (int r = 0; r < 4; ++r) {
            float t = fmaxf(fmaxf(sacc[0][r], sacc[1][r]), fmaxf(sacc[2][r], sacc[3][r]));
            #pragma unroll
            for (int msk = 1; msk <= 8; msk <<= 1)
                t = fmaxf(t, __shfl_xor(t, msk, 64));
            mnew[r]  = fmaxf(mrow[r], t);
            alpha[r] = __expf(mrow[r] - mnew[r]);
            mrow[r]  = mnew[r];
        }
        float psum[4] = {0.f, 0.f, 0.f, 0.f};
        #pragma unroll
        for (int nt = 0; nt < 4; ++nt) {
            #pragma unroll
            for (int r = 0; r < 4; ++r) {
                float p = __expf(sacc[nt][r] - mnew[r]);
                sacc[nt][r] = p;
                psum[r] += p;
            }
        }
        #pragma unroll
        for (int r = 0; r < 4; ++r) {
            float t = psum[r];
            #pragma unroll
            for (int msk = 1; msk <= 8; msk <<= 1)
                t += __shfl_xor(t, msk, 64);
            lrow[r] = lrow[r] * alpha[r] + t;
        }
        {
            f32x4 av; av[0] = alpha[0]; av[1] = alpha[1]; av[2] = alpha[2]; av[3] = alpha[3];
            #pragma unroll
            for (int dt = 0; dt < 4; ++dt) oacc[dt] *= av;
        }

        unsigned short* pw = &Pl[w][0];
        #pragma unroll
        for (int nt = 0; nt < 4; ++nt) {
            const int cc = nt * 16 + l15;
            #pragma unroll
            for (int r = 0; r < 4; ++r)
                pw[(lg * 4 + r) * PT_STRIDE + cc] = (unsigned short)f2bf(sacc[nt][r]);
        }

        #pragma unroll
        for (int s2 = 0; s2 < 2; ++s2) {
            bf16x8 pf = *(const bf16x8*)(pw + l15 * PT_STRIDE + s2 * 32 + lg * 8);
            #pragma unroll
            for (int dt = 0; dt < 4; ++dt) {
                const int d = dt * 16 + l15;
                bf16x8 vf = *(const bf16x8*)(Vt + vt_swz(d, s2 * 32 + lg * 8));
                oacc[dt] = __builtin_amdgcn_mfma_f32_16x16x32_bf16(pf, vf, oacc[dt], 0, 0, 0);
            }
        }
    }

    float inv4[4];
    #pragma unroll
    for (int r = 0; r < 4; ++r) inv4[r] = 1.f / lrow[r];
    unsigned short* ob = O + (size_t)(head * Sq + q0 + w * 16) * Dq;
    #pragma unroll
    for (int dt = 0; dt < 4; ++dt) {
        #pragma unroll
        for (int r = 0; r < 4; ++r)
            ob[(size_t)(lg * 4 + r) * Dq + dt * 16 + l15] = (unsigned short)f2bf(oacc[dt][r] * inv4[r]);
    }
}

extern "C" void kernel_launch(void* const* d_in, const int* in_sizes, int n_in,
                              void* d_out, int out_size, void* d_ws, size_t ws_size,
                              hipStream_t stream) {
    int* flag = (int*)d_ws;
    detect_dtype<<<dim3(1), dim3(64), 0, stream>>>((const unsigned int*)d_in[0], flag);
    if (ws_size >= WS_NEEDED) {
        unsigned short* img = (unsigned short*)((char*)d_ws + WS_IMG_OFF);
        convert_kv<<<dim3(IMG_TILES), dim3(256), 0, stream>>>(
            (const float*)d_in[1], (const float*)d_in[2], img, flag);
        fa_mfma_f32_pre<<<dim3(NBLK_P), dim3(256), 0, stream>>>(
            (const float*)d_in[0], img, (float*)d_out, flag);
    } else {
        fa_mfma_f32_fused<<<dim3(NBLK), dim3(256), 0, stream>>>(
            (const float*)d_in[0], (const float*)d_in[1],
            (const float*)d_in[2], (float*)d_out, flag);
    }
    fa_mfma_bf16<<<dim3(NBLK), dim3(256), 0, stream>>>(
        (const unsigned short*)d_in[0], (const unsigned short*)d_in[1],
        (const unsigned short*)d_in[2], (unsigned short*)d_out, flag);
}